// Round 6
// baseline (467.412 us; speedup 1.0000x reference)
//
#include <hip/hip_runtime.h>

// ---------------- problem constants ----------------
#define NN   10000     // nodes
#define E0   160000    // raw edges
#define ET   170000    // edges + self loops
#define DIN  165       // input channels
#define HID  1024      // 8 heads * 128
#define NH   8
#define MAXD 192       // max in-degree cap
#define GN   4         // nodes per block in gemm1

// dtypes (settled r5->r6): ALL float tensors f32, edge_index int32, OUTPUT f32.

__device__ __forceinline__ float bf2f(unsigned short u) {
    unsigned int i = ((unsigned int)u) << 16;
    return __builtin_bit_cast(float, i);
}
__device__ __forceinline__ unsigned short f2bf(float f) {
    unsigned int i = __builtin_bit_cast(unsigned int, f);
    i += 0x7fffu + ((i >> 16) & 1u);   // round-to-nearest-even
    return (unsigned short)(i >> 16);
}
__device__ __forceinline__ float fin(float x) {
    return fminf(fmaxf(x, -1e30f), 1e30f);
}
__device__ __forceinline__ int clampi(int s) {
    return min(max(s, 0), NN - 1);
}
__device__ __forceinline__ void unpack8(uint4 u, float* f) {
    f[0]=bf2f((unsigned short)(u.x)); f[1]=bf2f((unsigned short)(u.x>>16));
    f[2]=bf2f((unsigned short)(u.y)); f[3]=bf2f((unsigned short)(u.y>>16));
    f[4]=bf2f((unsigned short)(u.z)); f[5]=bf2f((unsigned short)(u.z>>16));
    f[6]=bf2f((unsigned short)(u.w)); f[7]=bf2f((unsigned short)(u.w>>16));
}

// ---------------- debug: encode a diagnostic value into the (f32) output ----------------
__global__ __launch_bounds__(256) void debug_fill(float* __restrict__ out, float val) {
    int i = blockIdx.x * 256 + threadIdx.x;
    if (i < NN) out[i] = val;
}

// ---------------- BN1: column stats over x [NN, DIN] f32 ----------------
__global__ __launch_bounds__(256) void bn1_stats(const float* __restrict__ x,
                                                 float* __restrict__ colsum, float* __restrict__ colsq) {
    int r0 = blockIdx.x * 125;
    int c = threadIdx.x;
    if (c >= DIN) return;
    float acc = 0.f, sq = 0.f;
    for (int r = r0; r < r0 + 125; ++r) {
        float v = x[(size_t)r * DIN + c];
        acc += v; sq += v * v;
    }
    atomicAdd(&colsum[c], acc);
    atomicAdd(&colsq[c], sq);
}

__global__ void bn1_scale(const float* __restrict__ colsum, const float* __restrict__ colsq,
                          const float* __restrict__ gamma, const float* __restrict__ beta,
                          float* __restrict__ A, float* __restrict__ B) {
    int c = threadIdx.x;
    if (c >= DIN) return;
    float mu  = colsum[c] * (1.f / NN);
    float var = fmaxf(colsq[c] * (1.f / NN) - mu * mu, 0.f);
    float a = gamma[c] * rsqrtf(var + 1e-5f);
    A[c] = a; B[c] = beta[c] - mu * a;
}

// write normalized input hn [NN, DIN] f32
__global__ __launch_bounds__(256) void bn1_apply(const float* __restrict__ x,
                                                 const float* __restrict__ A, const float* __restrict__ B,
                                                 float* __restrict__ hn) {
    int idx = blockIdx.x * 256 + threadIdx.x;
    if (idx >= NN * DIN) return;
    int c = idx % DIN;
    hn[idx] = fin(x[idx] * A[c] + B[c]);
}

// ---------------- GEMM1 (VALU, 4 nodes/block): hn @ W -> xl,xr bf16 ----------------
// W loads hoisted over GN nodes: W traffic /GN. hs reads are wave-broadcast (no conflicts).
__global__ __launch_bounds__(256) void gemm1_tiled(
    const float* __restrict__ hn,
    const float* __restrict__ Wl,   // [DIN,HID] f32
    const float* __restrict__ Wr,
    const float* __restrict__ bl,
    const float* __restrict__ br,
    unsigned short* __restrict__ xl,
    unsigned short* __restrict__ xr) {
    const int n0 = blockIdx.x * GN;
    const int t = threadIdx.x;
    __shared__ float hs[GN][DIN];
    for (int idx = t; idx < GN * DIN; idx += 256) {
        int nn = idx / DIN, k = idx - nn * DIN;
        hs[nn][k] = hn[(size_t)(n0 + nn) * DIN + k];
    }
    __syncthreads();
    const int c = t * 4;
    float accL[GN][4], accR[GN][4];
    #pragma unroll
    for (int nn = 0; nn < GN; ++nn)
        #pragma unroll
        for (int j = 0; j < 4; ++j) { accL[nn][j] = 0.f; accR[nn][j] = 0.f; }
    for (int k = 0; k < DIN; ++k) {
        const float4 wl = *(const float4*)(Wl + (size_t)k * HID + c);
        const float4 wr = *(const float4*)(Wr + (size_t)k * HID + c);
        #pragma unroll
        for (int nn = 0; nn < GN; ++nn) {
            const float s = hs[nn][k];
            accL[nn][0] = fmaf(s, wl.x, accL[nn][0]);
            accL[nn][1] = fmaf(s, wl.y, accL[nn][1]);
            accL[nn][2] = fmaf(s, wl.z, accL[nn][2]);
            accL[nn][3] = fmaf(s, wl.w, accL[nn][3]);
            accR[nn][0] = fmaf(s, wr.x, accR[nn][0]);
            accR[nn][1] = fmaf(s, wr.y, accR[nn][1]);
            accR[nn][2] = fmaf(s, wr.z, accR[nn][2]);
            accR[nn][3] = fmaf(s, wr.w, accR[nn][3]);
        }
    }
    const float4 blv = *(const float4*)(bl + c);
    const float4 brv = *(const float4*)(br + c);
    #pragma unroll
    for (int nn = 0; nn < GN; ++nn) {
        ushort4 ol, orr;
        ol.x  = f2bf(fin(accL[nn][0] + blv.x)); ol.y  = f2bf(fin(accL[nn][1] + blv.y));
        ol.z  = f2bf(fin(accL[nn][2] + blv.z)); ol.w  = f2bf(fin(accL[nn][3] + blv.w));
        orr.x = f2bf(fin(accR[nn][0] + brv.x)); orr.y = f2bf(fin(accR[nn][1] + brv.y));
        orr.z = f2bf(fin(accR[nn][2] + brv.z)); orr.w = f2bf(fin(accR[nn][3] + brv.w));
        *(ushort4*)(xl + (size_t)(n0 + nn) * HID + c) = ol;
        *(ushort4*)(xr + (size_t)(n0 + nn) * HID + c) = orr;
    }
}

// ---------------- edge counting-sort by dst ----------------
__global__ __launch_bounds__(256) void edge_hist(const int* __restrict__ ei, int* __restrict__ deg) {
    int e = blockIdx.x * 256 + threadIdx.x;
    if (e >= ET) return;
    int d = (e < E0) ? ei[E0 + e] : (e - E0);
    atomicAdd(&deg[clampi(d)], 1);
}

__global__ __launch_bounds__(1024) void scan_kernel(const int* __restrict__ deg,
                                                    int* __restrict__ offs, int* __restrict__ cur) {
    __shared__ int buf[1024];
    __shared__ int carry_s;
    int tid = threadIdx.x;
    if (tid == 0) carry_s = 0;
    __syncthreads();
    for (int base = 0; base < NN; base += 1024) {
        int i = base + tid;
        int v = (i < NN) ? deg[i] : 0;
        buf[tid] = v;
        __syncthreads();
        for (int s = 1; s < 1024; s <<= 1) {
            int t = (tid >= s) ? buf[tid - s] : 0;
            __syncthreads();
            buf[tid] += t;
            __syncthreads();
        }
        int carry = carry_s;
        if (i < NN) { int e = carry + buf[tid] - v; offs[i] = e; cur[i] = e; }
        __syncthreads();
        if (tid == 1023) carry_s = carry + buf[1023];
        __syncthreads();
    }
    if (tid == 0) offs[NN] = carry_s;
}

__global__ __launch_bounds__(256) void edge_scatter(const int* __restrict__ ei,
                                                    int* __restrict__ cur, int* __restrict__ ssrc) {
    int e = blockIdx.x * 256 + threadIdx.x;
    if (e >= ET) return;
    int s, d;
    if (e < E0) { s = ei[e]; d = ei[E0 + e]; }
    else        { s = e - E0; d = e - E0; }
    int pos = atomicAdd(&cur[clampi(d)], 1);
    if (pos >= 0 && pos < ET) ssrc[pos] = clampi(s);
}

// ---------------- GAT1 per-dst-node: logits + softmax + aggregate -> agg bf16 ----------------
// NOTE: agg aliases xr1 (row i read only by block i before sync#1; written after sync#3).
__global__ __launch_bounds__(256) void gat1_node(
    const unsigned short* __restrict__ xl1, const unsigned short* xr1,
    const float* __restrict__ att1, const float* __restrict__ bias1,
    const int* __restrict__ offs, const int* __restrict__ ssrc,
    unsigned short* agg) {
    const int i    = blockIdx.x;
    const int tid  = threadIdx.x;
    const int lane = tid & 63;
    const int wave = tid >> 6;
    __shared__ float a_lds[MAXD][NH];
    __shared__ float inv_lds[NH];
    __shared__ int   src_lds[MAXD];
    const int e0 = offs[i];
    const int deg = max(min(offs[i + 1] - e0, MAXD), 0);

    float xr_r[16], att_r[16];
    {
        const uint4* xp = (const uint4*)(xr1 + (size_t)i * HID + lane * 16);
        uint4 u0 = xp[0], u1 = xp[1];
        unpack8(u0, xr_r); unpack8(u1, xr_r + 8);
        const float4* ap = (const float4*)(att1 + lane * 16);
        float4 a0 = ap[0], a1 = ap[1], a2 = ap[2], a3 = ap[3];
        att_r[0]=a0.x; att_r[1]=a0.y; att_r[2]=a0.z; att_r[3]=a0.w;
        att_r[4]=a1.x; att_r[5]=a1.y; att_r[6]=a1.z; att_r[7]=a1.w;
        att_r[8]=a2.x; att_r[9]=a2.y; att_r[10]=a2.z; att_r[11]=a2.w;
        att_r[12]=a3.x; att_r[13]=a3.y; att_r[14]=a3.z; att_r[15]=a3.w;
    }
    for (int e = tid; e < deg; e += 256) src_lds[e] = clampi(ssrc[e0 + e]);
    __syncthreads();   // #1 — all xr1 reads complete

    for (int e = wave; e < deg; e += 4) {
        const int s = src_lds[e];
        const uint4* xp = (const uint4*)(xl1 + (size_t)s * HID + lane * 16);
        uint4 u0 = xp[0], u1 = xp[1];
        float xv[16];
        unpack8(u0, xv); unpack8(u1, xv + 8);
        float p = 0.f;
        #pragma unroll
        for (int j = 0; j < 16; ++j) {
            float v = xv[j] + xr_r[j];
            v = fmaxf(v, 0.2f * v);            // leaky_relu 0.2
            p = fmaf(att_r[j], v, p);
        }
        p += __shfl_xor(p, 1); p += __shfl_xor(p, 2); p += __shfl_xor(p, 4);
        if ((lane & 7) == 0) a_lds[e][lane >> 3] = fin(p);
    }
    __syncthreads();   // #2

    if (tid < NH) {
        float m = -1e30f;
        for (int e = 0; e < deg; ++e) m = fmaxf(m, a_lds[e][tid]);
        float s = 0.f;
        for (int e = 0; e < deg; ++e) {
            float a = __expf(fminf(a_lds[e][tid] - m, 0.f));
            a_lds[e][tid] = a; s += a;
        }
        inv_lds[tid] = 1.f / (s + 1e-16f);
    }
    __syncthreads();   // #3 — agg (= xr1) writes only after this

    const int h = tid >> 5;
    float ax = 0.f, ay = 0.f, az = 0.f, aw = 0.f;
    for (int e = 0; e < deg; ++e) {
        const float a = a_lds[e][h];
        const ushort4 u = *(const ushort4*)(xl1 + (size_t)src_lds[e] * HID + tid * 4);
        ax = fmaf(a, bf2f(u.x), ax);
        ay = fmaf(a, bf2f(u.y), ay);
        az = fmaf(a, bf2f(u.z), az);
        aw = fmaf(a, bf2f(u.w), aw);
    }
    const float inv = inv_lds[h];
    const float* bp = bias1 + tid * 4;
    ushort4 o;
    o.x = f2bf(fin(ax * inv + bp[0]));
    o.y = f2bf(fin(ay * inv + bp[1]));
    o.z = f2bf(fin(az * inv + bp[2]));
    o.w = f2bf(fin(aw * inv + bp[3]));
    *(ushort4*)(agg + (size_t)i * HID + tid * 4) = o;
}

// ---------------- BN2 over agg [NN,HID] bf16 ----------------
__global__ __launch_bounds__(256) void bn2_stats(const unsigned short* __restrict__ agg,
                                                 float* __restrict__ colsum, float* __restrict__ colsq) {
    int r0 = blockIdx.x * 125;
    int t = threadIdx.x;
    float s0=0,s1=0,s2=0,s3=0,q0=0,q1=0,q2=0,q3=0;
    for (int r = r0; r < r0 + 125; ++r) {
        const ushort4 u = *(const ushort4*)(agg + (size_t)r * HID + t * 4);
        float v0=bf2f(u.x), v1=bf2f(u.y), v2=bf2f(u.z), v3=bf2f(u.w);
        s0+=v0; q0+=v0*v0; s1+=v1; q1+=v1*v1;
        s2+=v2; q2+=v2*v2; s3+=v3; q3+=v3*v3;
    }
    atomicAdd(&colsum[t*4+0], s0); atomicAdd(&colsq[t*4+0], q0);
    atomicAdd(&colsum[t*4+1], s1); atomicAdd(&colsq[t*4+1], q1);
    atomicAdd(&colsum[t*4+2], s2); atomicAdd(&colsq[t*4+2], q2);
    atomicAdd(&colsum[t*4+3], s3); atomicAdd(&colsq[t*4+3], q3);
}

__global__ __launch_bounds__(1024) void bn2_scale(const float* __restrict__ colsum, const float* __restrict__ colsq,
                                                  const float* __restrict__ gamma, const float* __restrict__ beta,
                                                  float* __restrict__ A, float* __restrict__ B) {
    int c = threadIdx.x;
    float mu  = colsum[c] * (1.f / NN);
    float var = fmaxf(colsq[c] * (1.f / NN) - mu * mu, 0.f);
    float a = gamma[c] * rsqrtf(var + 1e-5f);
    A[c] = a; B[c] = beta[c] - mu * a;
}

// in-place: agg(bf16) -> h2(bf16), BN affine + leaky_relu(0.01)
__global__ __launch_bounds__(256) void bn2_apply(unsigned short* __restrict__ agg,
                                                 const float* __restrict__ A, const float* __restrict__ B) {
    int idx = blockIdx.x * 256 + threadIdx.x;
    int base = idx * 4;
    int c = base & (HID - 1);
    ushort4 u = *(const ushort4*)(agg + base);
    float4 a = *(const float4*)(A + c);
    float4 b = *(const float4*)(B + c);
    float o0 = bf2f(u.x) * a.x + b.x, o1 = bf2f(u.y) * a.y + b.y;
    float o2 = bf2f(u.z) * a.z + b.z, o3 = bf2f(u.w) * a.w + b.w;
    o0 = fmaxf(o0, 0.01f * o0); o1 = fmaxf(o1, 0.01f * o1);   // leaky 0.01
    o2 = fmaxf(o2, 0.01f * o2); o3 = fmaxf(o3, 0.01f * o3);
    ushort4 o; o.x = f2bf(fin(o0)); o.y = f2bf(fin(o1)); o.z = f2bf(fin(o2)); o.w = f2bf(fin(o3));
    *(ushort4*)(agg + base) = o;
}

// ---------------- GEMM2: h2 [NN,HID] @ W2 [HID,8] (x2) -> xl2,xr2 [NN,8] f32 ----------------
__global__ __launch_bounds__(256) void gemm2_kernel(
    const unsigned short* __restrict__ h2,
    const float* __restrict__ wl2, const float* __restrict__ bl2,
    const float* __restrict__ wr2, const float* __restrict__ br2,
    float* __restrict__ xl2, float* __restrict__ xr2) {
    const int lane = threadIdx.x & 63;
    const int wave = threadIdx.x >> 6;
    const int row = blockIdx.x * 4 + wave;
    float accL[8] = {0,0,0,0,0,0,0,0};
    float accR[8] = {0,0,0,0,0,0,0,0};
    const uint4* hp = (const uint4*)(h2 + (size_t)row * HID + lane * 16);
    uint4 u0 = hp[0], u1 = hp[1];
    float hv[16];
    unpack8(u0, hv); unpack8(u1, hv + 8);
    #pragma unroll
    for (int j = 0; j < 16; ++j) {
        const int c = lane * 16 + j;
        const float4 wla = *(const float4*)(wl2 + c * 8);
        const float4 wlb = *(const float4*)(wl2 + c * 8 + 4);
        const float4 wra = *(const float4*)(wr2 + c * 8);
        const float4 wrb = *(const float4*)(wr2 + c * 8 + 4);
        const float hvj = hv[j];
        accL[0] = fmaf(hvj, wla.x, accL[0]); accL[1] = fmaf(hvj, wla.y, accL[1]);
        accL[2] = fmaf(hvj, wla.z, accL[2]); accL[3] = fmaf(hvj, wla.w, accL[3]);
        accL[4] = fmaf(hvj, wlb.x, accL[4]); accL[5] = fmaf(hvj, wlb.y, accL[5]);
        accL[6] = fmaf(hvj, wlb.z, accL[6]); accL[7] = fmaf(hvj, wlb.w, accL[7]);
        accR[0] = fmaf(hvj, wra.x, accR[0]); accR[1] = fmaf(hvj, wra.y, accR[1]);
        accR[2] = fmaf(hvj, wra.z, accR[2]); accR[3] = fmaf(hvj, wra.w, accR[3]);
        accR[4] = fmaf(hvj, wrb.x, accR[4]); accR[5] = fmaf(hvj, wrb.y, accR[5]);
        accR[6] = fmaf(hvj, wrb.z, accR[6]); accR[7] = fmaf(hvj, wrb.w, accR[7]);
    }
    #pragma unroll
    for (int k = 0; k < 8; ++k) {
        for (int m = 1; m < 64; m <<= 1) {
            accL[k] += __shfl_xor(accL[k], m);
            accR[k] += __shfl_xor(accR[k], m);
        }
    }
    if (lane == 0) {
        #pragma unroll
        for (int k = 0; k < 8; ++k) {
            xl2[row * 8 + k] = fin(accL[k] + bl2[k]);
            xr2[row * 8 + k] = fin(accR[k] + br2[k]);
        }
    }
}

// ---------------- GAT2 per-node (wave per node), mean over heads -> f32 out ----------------
__global__ __launch_bounds__(256) void gat2_node(
    const float* __restrict__ xl2, const float* __restrict__ xr2,
    const float* __restrict__ att2, const float* __restrict__ bias2,
    const int* __restrict__ offs, const int* __restrict__ ssrc,
    float* __restrict__ out) {
    const int lane = threadIdx.x & 63;
    const int wave = threadIdx.x >> 6;
    const int i = blockIdx.x * 4 + wave;
    const int h = lane & 7, slot = lane >> 3;
    const int e0 = offs[i];
    const int e1 = max(offs[i + 1], e0);
    const float xr_h = xr2[i * 8 + h];
    const float att_h = att2[h];
    float m = -1e30f;
    for (int eb = e0; eb < e1; eb += 8) {
        int e = eb + slot;
        float lg = -1e30f;
        if (e < e1) {
            float v = xl2[clampi(ssrc[e]) * 8 + h] + xr_h;
            v = fmaxf(v, 0.2f * v);
            lg = fin(att_h * v);
        }
        m = fmaxf(m, lg);
    }
    m = fmaxf(m, __shfl_xor(m, 8)); m = fmaxf(m, __shfl_xor(m, 16)); m = fmaxf(m, __shfl_xor(m, 32));
    float ssum = 0.f, wsum = 0.f;
    for (int eb = e0; eb < e1; eb += 8) {
        int e = eb + slot;
        if (e < e1) {
            float xlv = xl2[clampi(ssrc[e]) * 8 + h];
            float v = xlv + xr_h;
            v = fmaxf(v, 0.2f * v);
            float a = __expf(fminf(fin(att_h * v) - m, 0.f));
            ssum += a; wsum += a * xlv;
        }
    }
    ssum += __shfl_xor(ssum, 8); ssum += __shfl_xor(ssum, 16); ssum += __shfl_xor(ssum, 32);
    wsum += __shfl_xor(wsum, 8); wsum += __shfl_xor(wsum, 16); wsum += __shfl_xor(wsum, 32);
    float v = fin(wsum / (ssum + 1e-16f));
    v += __shfl_xor(v, 1); v += __shfl_xor(v, 2); v += __shfl_xor(v, 4);
    if (lane == 0) out[i] = fin(v * 0.125f + bias2[0]);
}

// ---------------- launch ----------------
extern "C" void kernel_launch(void* const* d_in, const int* in_sizes, int n_in,
                              void* d_out, int out_size, void* d_ws, size_t ws_size,
                              hipStream_t stream) {
    float* out = (float*)d_out;   // reference output dtype is float32

    static const int expected[18] = {
        NN * DIN, DIN, DIN, DIN * HID, HID, DIN * HID, HID, HID, HID,
        HID, HID, HID * NH, NH, HID * NH, NH, NH, 1, 2 * E0
    };
    if (n_in != 18) {
        debug_fill<<<(NN + 255) / 256, 256, 0, stream>>>(out, 8192.f + 64.f * (float)n_in);
        return;
    }
    for (int i = 0; i < 18; ++i) {
        if (in_sizes[i] != expected[i]) {
            debug_fill<<<(NN + 255) / 256, 256, 0, stream>>>(out, 4096.f + 32.f * (float)i);
            return;
        }
    }

    const float* x      = (const float*)d_in[0];
    const float* gamma1 = (const float*)d_in[1];
    const float* beta1  = (const float*)d_in[2];
    const float* Wl1    = (const float*)d_in[3];
    const float* bl1    = (const float*)d_in[4];
    const float* Wr1    = (const float*)d_in[5];
    const float* br1    = (const float*)d_in[6];
    const float* att1   = (const float*)d_in[7];
    const float* bias1  = (const float*)d_in[8];
    const float* gamma2 = (const float*)d_in[9];
    const float* beta2  = (const float*)d_in[10];
    const float* Wl2    = (const float*)d_in[11];
    const float* bl2    = (const float*)d_in[12];
    const float* Wr2    = (const float*)d_in[13];
    const float* br2    = (const float*)d_in[14];
    const float* att2   = (const float*)d_in[15];
    const float* bias2  = (const float*)d_in[16];
    const int*   ei     = (const int*)d_in[17];

    char* p = (char*)d_ws;
    auto alloc = [&](size_t bytes) -> void* {
        void* r = (void*)p;
        p += (bytes + 255) & ~(size_t)255;
        return r;
    };
    unsigned short* xl1  = (unsigned short*)alloc((size_t)NN * HID * 2);  // 20.48 MB
    unsigned short* xr1  = (unsigned short*)alloc((size_t)NN * HID * 2);  // 20.48 MB
    unsigned short* agg  = xr1;                                           // ALIAS (see gat1_node)
    float*          hn   = (float*)alloc((size_t)NN * DIN * 4);           // 6.60 MB
    float*          xl2  = (float*)alloc((size_t)NN * 8 * 4);
    float*          xr2  = (float*)alloc((size_t)NN * 8 * 4);
    float*          A1   = (float*)alloc(DIN * 4);
    float*          B1   = (float*)alloc(DIN * 4);
    float*          A2   = (float*)alloc(HID * 4);
    float*          B2   = (float*)alloc(HID * 4);
    int*            offs = (int*)alloc((NN + 1) * 4);
    int*            cur  = (int*)alloc(NN * 4);
    int*            ssrc = (int*)alloc(ET * 4);
    char* zbase = p;
    float* colsum1 = (float*)alloc(DIN * 4);
    float* colsq1  = (float*)alloc(DIN * 4);
    float* colsum2 = (float*)alloc(HID * 4);
    float* colsq2  = (float*)alloc(HID * 4);
    int*   deg     = (int*)alloc(NN * 4);
    size_t zlen = (size_t)(p - zbase);
    hipMemsetAsync(zbase, 0, zlen, stream);

    // BN1 -> hn [NN,DIN] f32
    bn1_stats<<<80, 256, 0, stream>>>(x, colsum1, colsq1);
    bn1_scale<<<1, 256, 0, stream>>>(colsum1, colsq1, gamma1, beta1, A1, B1);
    bn1_apply<<<(NN * DIN + 255) / 256, 256, 0, stream>>>(x, A1, B1, hn);
    // GEMM1 (VALU, W-reuse over 4 nodes) -> xl1, xr1 (bf16)
    gemm1_tiled<<<NN / GN, 256, 0, stream>>>(hn, Wl1, Wr1, bl1, br1, xl1, xr1);
    // edge sort by dst
    edge_hist<<<(ET + 255) / 256, 256, 0, stream>>>(ei, deg);
    scan_kernel<<<1, 1024, 0, stream>>>(deg, offs, cur);
    edge_scatter<<<(ET + 255) / 256, 256, 0, stream>>>(ei, cur, ssrc);
    // GAT1 -> agg (bf16, +bias1) ; agg aliases xr1
    gat1_node<<<NN, 256, 0, stream>>>(xl1, xr1, att1, bias1, offs, ssrc, agg);
    // BN2 + leaky(0.01) in-place on agg -> h2
    bn2_stats<<<80, 256, 0, stream>>>(agg, colsum2, colsq2);
    bn2_scale<<<1, 1024, 0, stream>>>(colsum2, colsq2, gamma2, beta2, A2, B2);
    bn2_apply<<<(NN * HID / 4 + 255) / 256, 256, 0, stream>>>(agg, A2, B2);
    // GEMM2 -> xl2, xr2
    gemm2_kernel<<<NN / 4, 256, 0, stream>>>(agg, Wl2, bl2, Wr2, br2, xl2, xr2);
    // GAT2 -> out (f32)
    gat2_node<<<NN / 4, 256, 0, stream>>>(xl2, xr2, att2, bias2, offs, ssrc, out);
}

// Round 7
// 430.275 us; speedup vs baseline: 1.0863x; 1.0863x over previous
//
#include <hip/hip_runtime.h>

// ---------------- problem constants ----------------
#define NN   10000     // nodes
#define E0   160000    // raw edges
#define ET   170000    // edges + self loops
#define DIN  165       // input channels
#define KP   192       // DIN padded to 32x for MFMA K-loop
#define HID  1024      // 8 heads * 128
#define NH   8
#define MAXD 192       // max in-degree cap

// dtypes (settled r6): ALL float tensors f32, edge_index int32, OUTPUT f32.

typedef __bf16 bf16x8 __attribute__((ext_vector_type(8)));
typedef float  f32x4  __attribute__((ext_vector_type(4)));

__device__ __forceinline__ float bf2f(unsigned short u) {
    unsigned int i = ((unsigned int)u) << 16;
    return __builtin_bit_cast(float, i);
}
__device__ __forceinline__ unsigned short f2bf(float f) {
    unsigned int i = __builtin_bit_cast(unsigned int, f);
    i += 0x7fffu + ((i >> 16) & 1u);   // round-to-nearest-even
    return (unsigned short)(i >> 16);
}
__device__ __forceinline__ float fin(float x) {
    return fminf(fmaxf(x, -1e30f), 1e30f);
}
__device__ __forceinline__ int clampi(int s) {
    return min(max(s, 0), NN - 1);
}
__device__ __forceinline__ void unpack8(uint4 u, float* f) {
    f[0]=bf2f((unsigned short)(u.x)); f[1]=bf2f((unsigned short)(u.x>>16));
    f[2]=bf2f((unsigned short)(u.y)); f[3]=bf2f((unsigned short)(u.y>>16));
    f[4]=bf2f((unsigned short)(u.z)); f[5]=bf2f((unsigned short)(u.z>>16));
    f[6]=bf2f((unsigned short)(u.w)); f[7]=bf2f((unsigned short)(u.w>>16));
}

// ---------------- debug ----------------
__global__ __launch_bounds__(256) void debug_fill(float* __restrict__ out, float val) {
    int i = blockIdx.x * 256 + threadIdx.x;
    if (i < NN) out[i] = val;
}

// ---------------- BN1: column stats over x [NN, DIN] f32 ----------------
__global__ __launch_bounds__(256) void bn1_stats(const float* __restrict__ x,
                                                 float* __restrict__ colsum, float* __restrict__ colsq) {
    int r0 = blockIdx.x * 125;
    int c = threadIdx.x;
    if (c >= DIN) return;
    float acc = 0.f, sq = 0.f;
    for (int r = r0; r < r0 + 125; ++r) {
        float v = x[(size_t)r * DIN + c];
        acc += v; sq += v * v;
    }
    atomicAdd(&colsum[c], acc);
    atomicAdd(&colsq[c], sq);
}

__global__ void bn1_scale(const float* __restrict__ colsum, const float* __restrict__ colsq,
                          const float* __restrict__ gamma, const float* __restrict__ beta,
                          float* __restrict__ A, float* __restrict__ B) {
    int c = threadIdx.x;
    if (c >= DIN) return;
    float mu  = colsum[c] * (1.f / NN);
    float var = fmaxf(colsq[c] * (1.f / NN) - mu * mu, 0.f);
    float a = gamma[c] * rsqrtf(var + 1e-5f);
    A[c] = a; B[c] = beta[c] - mu * a;
}

// write normalized, K-padded input hn [NN, KP] bf16
__global__ __launch_bounds__(256) void bn1_apply(const float* __restrict__ x,
                                                 const float* __restrict__ A, const float* __restrict__ B,
                                                 unsigned short* __restrict__ hn) {
    int idx = blockIdx.x * 256 + threadIdx.x;   // NN*KP threads
    if (idx >= NN * KP) return;
    int r = idx / KP, c = idx - r * KP;
    float v = 0.f;
    if (c < DIN) v = fin(x[(size_t)r * DIN + c] * A[c] + B[c]);
    hn[idx] = f2bf(v);
}

// ---------------- transpose+pad+cvt W1: f32 [DIN,HID] -> bf16 [HID,KP] ----------------
__global__ __launch_bounds__(256) void w1_transpose(const float* __restrict__ wl,
                                                    const float* __restrict__ wr,
                                                    unsigned short* __restrict__ wlt,
                                                    unsigned short* __restrict__ wrt) {
    int idx = blockIdx.x * 256 + threadIdx.x;   // HID*KP
    if (idx >= HID * KP) return;
    int n = idx / KP, k = idx - n * KP;
    wlt[idx] = (k < DIN) ? f2bf(wl[(size_t)k * HID + n]) : (unsigned short)0;
    wrt[idx] = (k < DIN) ? f2bf(wr[(size_t)k * HID + n]) : (unsigned short)0;
}

// ---------------- GEMM1 (MFMA): hn [NN,KP] @ W [KP,HID] -> xl,xr bf16 ----------------
// A frag: lane holds A[m=lane&15][k=(lane>>4)*8+j]; B frag: B[k=(lane>>4)*8+j][n=lane&15];
// D: row=(lane>>4)*4+r, col=lane&15   (m89/m91-verified C/D layout)
__global__ __launch_bounds__(256) void gemm1_kernel(
    const unsigned short* __restrict__ hn,
    const unsigned short* __restrict__ wlt,  // [HID][KP] bf16
    const unsigned short* __restrict__ wrt,
    const float* __restrict__ bl,
    const float* __restrict__ br,
    unsigned short* __restrict__ xl,
    unsigned short* __restrict__ xr) {
    const int lane = threadIdx.x & 63;
    const int wave = threadIdx.x >> 6;
    const int col  = lane & 15;
    const int q    = lane >> 4;
    const int m0 = blockIdx.x * 64 + wave * 16;
    const int n0 = blockIdx.y * 128;
    const int am = m0 + col;
    f32x4 accL[8], accR[8];
    #pragma unroll
    for (int i = 0; i < 8; ++i)
        for (int r = 0; r < 4; ++r) { accL[i][r] = 0.f; accR[i][r] = 0.f; }
    const bool aok = (am < NN);
    #pragma unroll
    for (int kt = 0; kt < 6; ++kt) {
        const int kk = kt * 32 + q * 8;
        uint4 au = make_uint4(0u, 0u, 0u, 0u);
        if (aok) au = *(const uint4*)(hn + (size_t)am * KP + kk);
        bf16x8 af = __builtin_bit_cast(bf16x8, au);
        #pragma unroll
        for (int nt = 0; nt < 8; ++nt) {
            const int nc = n0 + nt * 16 + col;
            bf16x8 bfl = __builtin_bit_cast(bf16x8, *(const uint4*)(wlt + (size_t)nc * KP + kk));
            accL[nt] = __builtin_amdgcn_mfma_f32_16x16x32_bf16(af, bfl, accL[nt], 0, 0, 0);
            bf16x8 bfr = __builtin_bit_cast(bf16x8, *(const uint4*)(wrt + (size_t)nc * KP + kk));
            accR[nt] = __builtin_amdgcn_mfma_f32_16x16x32_bf16(af, bfr, accR[nt], 0, 0, 0);
        }
    }
    #pragma unroll
    for (int nt = 0; nt < 8; ++nt) {
        const int nc = n0 + nt * 16 + col;
        const float bLv = bl[nc];
        const float bRv = br[nc];
        #pragma unroll
        for (int r = 0; r < 4; ++r) {
            const int row = m0 + q * 4 + r;
            if (row < NN) {
                xl[(size_t)row * HID + nc] = f2bf(fin(accL[nt][r] + bLv));
                xr[(size_t)row * HID + nc] = f2bf(fin(accR[nt][r] + bRv));
            }
        }
    }
}

// ---------------- edge counting-sort by dst ----------------
__global__ __launch_bounds__(256) void edge_hist(const int* __restrict__ ei, int* __restrict__ deg) {
    int e = blockIdx.x * 256 + threadIdx.x;
    if (e >= ET) return;
    int d = (e < E0) ? ei[E0 + e] : (e - E0);
    atomicAdd(&deg[clampi(d)], 1);
}

__global__ __launch_bounds__(1024) void scan_kernel(const int* __restrict__ deg,
                                                    int* __restrict__ offs, int* __restrict__ cur) {
    __shared__ int buf[1024];
    __shared__ int carry_s;
    int tid = threadIdx.x;
    if (tid == 0) carry_s = 0;
    __syncthreads();
    for (int base = 0; base < NN; base += 1024) {
        int i = base + tid;
        int v = (i < NN) ? deg[i] : 0;
        buf[tid] = v;
        __syncthreads();
        for (int s = 1; s < 1024; s <<= 1) {
            int t = (tid >= s) ? buf[tid - s] : 0;
            __syncthreads();
            buf[tid] += t;
            __syncthreads();
        }
        int carry = carry_s;
        if (i < NN) { int e = carry + buf[tid] - v; offs[i] = e; cur[i] = e; }
        __syncthreads();
        if (tid == 1023) carry_s = carry + buf[1023];
        __syncthreads();
    }
    if (tid == 0) offs[NN] = carry_s;
}

__global__ __launch_bounds__(256) void edge_scatter(const int* __restrict__ ei,
                                                    int* __restrict__ cur, int* __restrict__ ssrc) {
    int e = blockIdx.x * 256 + threadIdx.x;
    if (e >= ET) return;
    int s, d;
    if (e < E0) { s = ei[e]; d = ei[E0 + e]; }
    else        { s = e - E0; d = e - E0; }
    int pos = atomicAdd(&cur[clampi(d)], 1);
    if (pos >= 0 && pos < ET) ssrc[pos] = clampi(s);
}

// ---------------- GAT1 per-dst-node: logits + softmax + aggregate -> agg bf16 ----------------
// NOTE: agg aliases xr1 (row i read only by block i before sync#1; written after sync#3).
__global__ __launch_bounds__(256) void gat1_node(
    const unsigned short* __restrict__ xl1, const unsigned short* xr1,
    const float* __restrict__ att1, const float* __restrict__ bias1,
    const int* __restrict__ offs, const int* __restrict__ ssrc,
    unsigned short* agg) {
    const int i    = blockIdx.x;
    const int tid  = threadIdx.x;
    const int lane = tid & 63;
    const int wave = tid >> 6;
    __shared__ float a_lds[MAXD][NH];
    __shared__ float inv_lds[NH];
    __shared__ int   src_lds[MAXD];
    const int e0 = offs[i];
    const int deg = max(min(offs[i + 1] - e0, MAXD), 0);

    float xr_r[16], att_r[16];
    {
        const uint4* xp = (const uint4*)(xr1 + (size_t)i * HID + lane * 16);
        uint4 u0 = xp[0], u1 = xp[1];
        unpack8(u0, xr_r); unpack8(u1, xr_r + 8);
        const float4* ap = (const float4*)(att1 + lane * 16);
        float4 a0 = ap[0], a1 = ap[1], a2 = ap[2], a3 = ap[3];
        att_r[0]=a0.x; att_r[1]=a0.y; att_r[2]=a0.z; att_r[3]=a0.w;
        att_r[4]=a1.x; att_r[5]=a1.y; att_r[6]=a1.z; att_r[7]=a1.w;
        att_r[8]=a2.x; att_r[9]=a2.y; att_r[10]=a2.z; att_r[11]=a2.w;
        att_r[12]=a3.x; att_r[13]=a3.y; att_r[14]=a3.z; att_r[15]=a3.w;
    }
    for (int e = tid; e < deg; e += 256) src_lds[e] = clampi(ssrc[e0 + e]);
    __syncthreads();   // #1 — all xr1 reads complete

    for (int e = wave; e < deg; e += 4) {
        const int s = src_lds[e];
        const uint4* xp = (const uint4*)(xl1 + (size_t)s * HID + lane * 16);
        uint4 u0 = xp[0], u1 = xp[1];
        float xv[16];
        unpack8(u0, xv); unpack8(u1, xv + 8);
        float p = 0.f;
        #pragma unroll
        for (int j = 0; j < 16; ++j) {
            float v = xv[j] + xr_r[j];
            v = fmaxf(v, 0.2f * v);            // leaky_relu 0.2
            p = fmaf(att_r[j], v, p);
        }
        p += __shfl_xor(p, 1); p += __shfl_xor(p, 2); p += __shfl_xor(p, 4);
        if ((lane & 7) == 0) a_lds[e][lane >> 3] = fin(p);
    }
    __syncthreads();   // #2

    if (tid < NH) {
        float m = -1e30f;
        for (int e = 0; e < deg; ++e) m = fmaxf(m, a_lds[e][tid]);
        float s = 0.f;
        for (int e = 0; e < deg; ++e) {
            float a = __expf(fminf(a_lds[e][tid] - m, 0.f));
            a_lds[e][tid] = a; s += a;
        }
        inv_lds[tid] = 1.f / (s + 1e-16f);
    }
    __syncthreads();   // #3 — agg (= xr1) writes only after this

    const int h = tid >> 5;
    float ax = 0.f, ay = 0.f, az = 0.f, aw = 0.f;
    for (int e = 0; e < deg; ++e) {
        const float a = a_lds[e][h];
        const ushort4 u = *(const ushort4*)(xl1 + (size_t)src_lds[e] * HID + tid * 4);
        ax = fmaf(a, bf2f(u.x), ax);
        ay = fmaf(a, bf2f(u.y), ay);
        az = fmaf(a, bf2f(u.z), az);
        aw = fmaf(a, bf2f(u.w), aw);
    }
    const float inv = inv_lds[h];
    const float* bp = bias1 + tid * 4;
    ushort4 o;
    o.x = f2bf(fin(ax * inv + bp[0]));
    o.y = f2bf(fin(ay * inv + bp[1]));
    o.z = f2bf(fin(az * inv + bp[2]));
    o.w = f2bf(fin(aw * inv + bp[3]));
    *(ushort4*)(agg + (size_t)i * HID + tid * 4) = o;
}

// ---------------- BN2 over agg [NN,HID] bf16 ----------------
__global__ __launch_bounds__(256) void bn2_stats(const unsigned short* __restrict__ agg,
                                                 float* __restrict__ colsum, float* __restrict__ colsq) {
    int r0 = blockIdx.x * 125;
    int t = threadIdx.x;
    float s0=0,s1=0,s2=0,s3=0,q0=0,q1=0,q2=0,q3=0;
    for (int r = r0; r < r0 + 125; ++r) {
        const ushort4 u = *(const ushort4*)(agg + (size_t)r * HID + t * 4);
        float v0=bf2f(u.x), v1=bf2f(u.y), v2=bf2f(u.z), v3=bf2f(u.w);
        s0+=v0; q0+=v0*v0; s1+=v1; q1+=v1*v1;
        s2+=v2; q2+=v2*v2; s3+=v3; q3+=v3*v3;
    }
    atomicAdd(&colsum[t*4+0], s0); atomicAdd(&colsq[t*4+0], q0);
    atomicAdd(&colsum[t*4+1], s1); atomicAdd(&colsq[t*4+1], q1);
    atomicAdd(&colsum[t*4+2], s2); atomicAdd(&colsq[t*4+2], q2);
    atomicAdd(&colsum[t*4+3], s3); atomicAdd(&colsq[t*4+3], q3);
}

__global__ __launch_bounds__(1024) void bn2_scale(const float* __restrict__ colsum, const float* __restrict__ colsq,
                                                  const float* __restrict__ gamma, const float* __restrict__ beta,
                                                  float* __restrict__ A, float* __restrict__ B) {
    int c = threadIdx.x;
    float mu  = colsum[c] * (1.f / NN);
    float var = fmaxf(colsq[c] * (1.f / NN) - mu * mu, 0.f);
    float a = gamma[c] * rsqrtf(var + 1e-5f);
    A[c] = a; B[c] = beta[c] - mu * a;
}

// in-place: agg(bf16) -> h2(bf16), BN affine + leaky_relu(0.01)
__global__ __launch_bounds__(256) void bn2_apply(unsigned short* __restrict__ agg,
                                                 const float* __restrict__ A, const float* __restrict__ B) {
    int idx = blockIdx.x * 256 + threadIdx.x;
    int base = idx * 4;
    int c = base & (HID - 1);
    ushort4 u = *(const ushort4*)(agg + base);
    float4 a = *(const float4*)(A + c);
    float4 b = *(const float4*)(B + c);
    float o0 = bf2f(u.x) * a.x + b.x, o1 = bf2f(u.y) * a.y + b.y;
    float o2 = bf2f(u.z) * a.z + b.z, o3 = bf2f(u.w) * a.w + b.w;
    o0 = fmaxf(o0, 0.01f * o0); o1 = fmaxf(o1, 0.01f * o1);   // leaky 0.01
    o2 = fmaxf(o2, 0.01f * o2); o3 = fmaxf(o3, 0.01f * o3);
    ushort4 o; o.x = f2bf(fin(o0)); o.y = f2bf(fin(o1)); o.z = f2bf(fin(o2)); o.w = f2bf(fin(o3));
    *(ushort4*)(agg + base) = o;
}

// ---------------- GEMM2: h2 [NN,HID] @ W2 [HID,8] (x2) -> xl2,xr2 [NN,8] f32 ----------------
__global__ __launch_bounds__(256) void gemm2_kernel(
    const unsigned short* __restrict__ h2,
    const float* __restrict__ wl2, const float* __restrict__ bl2,
    const float* __restrict__ wr2, const float* __restrict__ br2,
    float* __restrict__ xl2, float* __restrict__ xr2) {
    const int lane = threadIdx.x & 63;
    const int wave = threadIdx.x >> 6;
    const int row = blockIdx.x * 4 + wave;
    float accL[8] = {0,0,0,0,0,0,0,0};
    float accR[8] = {0,0,0,0,0,0,0,0};
    const uint4* hp = (const uint4*)(h2 + (size_t)row * HID + lane * 16);
    uint4 u0 = hp[0], u1 = hp[1];
    float hv[16];
    unpack8(u0, hv); unpack8(u1, hv + 8);
    #pragma unroll
    for (int j = 0; j < 16; ++j) {
        const int c = lane * 16 + j;
        const float4 wla = *(const float4*)(wl2 + c * 8);
        const float4 wlb = *(const float4*)(wl2 + c * 8 + 4);
        const float4 wra = *(const float4*)(wr2 + c * 8);
        const float4 wrb = *(const float4*)(wr2 + c * 8 + 4);
        const float hvj = hv[j];
        accL[0] = fmaf(hvj, wla.x, accL[0]); accL[1] = fmaf(hvj, wla.y, accL[1]);
        accL[2] = fmaf(hvj, wla.z, accL[2]); accL[3] = fmaf(hvj, wla.w, accL[3]);
        accL[4] = fmaf(hvj, wlb.x, accL[4]); accL[5] = fmaf(hvj, wlb.y, accL[5]);
        accL[6] = fmaf(hvj, wlb.z, accL[6]); accL[7] = fmaf(hvj, wlb.w, accL[7]);
        accR[0] = fmaf(hvj, wra.x, accR[0]); accR[1] = fmaf(hvj, wra.y, accR[1]);
        accR[2] = fmaf(hvj, wra.z, accR[2]); accR[3] = fmaf(hvj, wra.w, accR[3]);
        accR[4] = fmaf(hvj, wrb.x, accR[4]); accR[5] = fmaf(hvj, wrb.y, accR[5]);
        accR[6] = fmaf(hvj, wrb.z, accR[6]); accR[7] = fmaf(hvj, wrb.w, accR[7]);
    }
    #pragma unroll
    for (int k = 0; k < 8; ++k) {
        for (int m = 1; m < 64; m <<= 1) {
            accL[k] += __shfl_xor(accL[k], m);
            accR[k] += __shfl_xor(accR[k], m);
        }
    }
    if (lane == 0) {
        #pragma unroll
        for (int k = 0; k < 8; ++k) {
            xl2[row * 8 + k] = fin(accL[k] + bl2[k]);
            xr2[row * 8 + k] = fin(accR[k] + br2[k]);
        }
    }
}

// ---------------- GAT2 per-node (wave per node), mean over heads -> f32 out ----------------
__global__ __launch_bounds__(256) void gat2_node(
    const float* __restrict__ xl2, const float* __restrict__ xr2,
    const float* __restrict__ att2, const float* __restrict__ bias2,
    const int* __restrict__ offs, const int* __restrict__ ssrc,
    float* __restrict__ out) {
    const int lane = threadIdx.x & 63;
    const int wave = threadIdx.x >> 6;
    const int i = blockIdx.x * 4 + wave;
    const int h = lane & 7, slot = lane >> 3;
    const int e0 = offs[i];
    const int e1 = max(offs[i + 1], e0);
    const float xr_h = xr2[i * 8 + h];
    const float att_h = att2[h];
    float m = -1e30f;
    for (int eb = e0; eb < e1; eb += 8) {
        int e = eb + slot;
        float lg = -1e30f;
        if (e < e1) {
            float v = xl2[clampi(ssrc[e]) * 8 + h] + xr_h;
            v = fmaxf(v, 0.2f * v);
            lg = fin(att_h * v);
        }
        m = fmaxf(m, lg);
    }
    m = fmaxf(m, __shfl_xor(m, 8)); m = fmaxf(m, __shfl_xor(m, 16)); m = fmaxf(m, __shfl_xor(m, 32));
    float ssum = 0.f, wsum = 0.f;
    for (int eb = e0; eb < e1; eb += 8) {
        int e = eb + slot;
        if (e < e1) {
            float xlv = xl2[clampi(ssrc[e]) * 8 + h];
            float v = xlv + xr_h;
            v = fmaxf(v, 0.2f * v);
            float a = __expf(fminf(fin(att_h * v) - m, 0.f));
            ssum += a; wsum += a * xlv;
        }
    }
    ssum += __shfl_xor(ssum, 8); ssum += __shfl_xor(ssum, 16); ssum += __shfl_xor(ssum, 32);
    wsum += __shfl_xor(wsum, 8); wsum += __shfl_xor(wsum, 16); wsum += __shfl_xor(wsum, 32);
    float v = fin(wsum / (ssum + 1e-16f));
    v += __shfl_xor(v, 1); v += __shfl_xor(v, 2); v += __shfl_xor(v, 4);
    if (lane == 0) out[i] = fin(v * 0.125f + bias2[0]);
}

// ---------------- launch ----------------
extern "C" void kernel_launch(void* const* d_in, const int* in_sizes, int n_in,
                              void* d_out, int out_size, void* d_ws, size_t ws_size,
                              hipStream_t stream) {
    float* out = (float*)d_out;   // reference output dtype is float32

    static const int expected[18] = {
        NN * DIN, DIN, DIN, DIN * HID, HID, DIN * HID, HID, HID, HID,
        HID, HID, HID * NH, NH, HID * NH, NH, NH, 1, 2 * E0
    };
    if (n_in != 18) {
        debug_fill<<<(NN + 255) / 256, 256, 0, stream>>>(out, 8192.f + 64.f * (float)n_in);
        return;
    }
    for (int i = 0; i < 18; ++i) {
        if (in_sizes[i] != expected[i]) {
            debug_fill<<<(NN + 255) / 256, 256, 0, stream>>>(out, 4096.f + 32.f * (float)i);
            return;
        }
    }

    const float* x      = (const float*)d_in[0];
    const float* gamma1 = (const float*)d_in[1];
    const float* beta1  = (const float*)d_in[2];
    const float* Wl1    = (const float*)d_in[3];
    const float* bl1    = (const float*)d_in[4];
    const float* Wr1    = (const float*)d_in[5];
    const float* br1    = (const float*)d_in[6];
    const float* att1   = (const float*)d_in[7];
    const float* bias1  = (const float*)d_in[8];
    const float* gamma2 = (const float*)d_in[9];
    const float* beta2  = (const float*)d_in[10];
    const float* Wl2    = (const float*)d_in[11];
    const float* bl2    = (const float*)d_in[12];
    const float* Wr2    = (const float*)d_in[13];
    const float* br2    = (const float*)d_in[14];
    const float* att2   = (const float*)d_in[15];
    const float* bias2  = (const float*)d_in[16];
    const int*   ei     = (const int*)d_in[17];

    char* p = (char*)d_ws;
    auto alloc = [&](size_t bytes) -> void* {
        void* r = (void*)p;
        p += (bytes + 255) & ~(size_t)255;
        return r;
    };
    unsigned short* xl1  = (unsigned short*)alloc((size_t)NN * HID * 2);  // 20.48 MB
    unsigned short* xr1  = (unsigned short*)alloc((size_t)NN * HID * 2);  // 20.48 MB
    unsigned short* agg  = xr1;                                           // ALIAS (see gat1_node)
    unsigned short* hn   = (unsigned short*)alloc((size_t)NN * KP * 2);   // 3.84 MB
    unsigned short* wlt  = (unsigned short*)alloc((size_t)HID * KP * 2);  // 0.39 MB
    unsigned short* wrt  = (unsigned short*)alloc((size_t)HID * KP * 2);  // 0.39 MB
    float*          xl2  = (float*)alloc((size_t)NN * 8 * 4);
    float*          xr2  = (float*)alloc((size_t)NN * 8 * 4);
    float*          A1   = (float*)alloc(DIN * 4);
    float*          B1   = (float*)alloc(DIN * 4);
    float*          A2   = (float*)alloc(HID * 4);
    float*          B2   = (float*)alloc(HID * 4);
    int*            offs = (int*)alloc((NN + 1) * 4);
    int*            cur  = (int*)alloc(NN * 4);
    int*            ssrc = (int*)alloc(ET * 4);
    char* zbase = p;
    float* colsum1 = (float*)alloc(DIN * 4);
    float* colsq1  = (float*)alloc(DIN * 4);
    float* colsum2 = (float*)alloc(HID * 4);
    float* colsq2  = (float*)alloc(HID * 4);
    int*   deg     = (int*)alloc(NN * 4);
    size_t zlen = (size_t)(p - zbase);
    hipMemsetAsync(zbase, 0, zlen, stream);

    // BN1 -> hn [NN,KP] bf16
    bn1_stats<<<80, 256, 0, stream>>>(x, colsum1, colsq1);
    bn1_scale<<<1, 256, 0, stream>>>(colsum1, colsq1, gamma1, beta1, A1, B1);
    bn1_apply<<<(NN * KP + 255) / 256, 256, 0, stream>>>(x, A1, B1, hn);
    // W1 transpose+pad+cvt (f32 -> bf16 [HID,KP])
    w1_transpose<<<(HID * KP + 255) / 256, 256, 0, stream>>>(Wl1, Wr1, wlt, wrt);
    // GEMM1 (MFMA bf16) -> xl1, xr1
    gemm1_kernel<<<dim3((NN + 63) / 64, HID / 128), 256, 0, stream>>>(hn, wlt, wrt, bl1, br1, xl1, xr1);
    // edge sort by dst
    edge_hist<<<(ET + 255) / 256, 256, 0, stream>>>(ei, deg);
    scan_kernel<<<1, 1024, 0, stream>>>(deg, offs, cur);
    edge_scatter<<<(ET + 255) / 256, 256, 0, stream>>>(ei, cur, ssrc);
    // GAT1 -> agg (bf16, +bias1) ; agg aliases xr1
    gat1_node<<<NN, 256, 0, stream>>>(xl1, xr1, att1, bias1, offs, ssrc, agg);
    // BN2 + leaky(0.01) in-place on agg -> h2
    bn2_stats<<<80, 256, 0, stream>>>(agg, colsum2, colsq2);
    bn2_scale<<<1, 1024, 0, stream>>>(colsum2, colsq2, gamma2, beta2, A2, B2);
    bn2_apply<<<(NN * HID / 4 + 255) / 256, 256, 0, stream>>>(agg, A2, B2);
    // GEMM2 -> xl2, xr2
    gemm2_kernel<<<NN / 4, 256, 0, stream>>>(agg, Wl2, bl2, Wr2, br2, xl2, xr2);
    // GAT2 -> out (f32)
    gat2_node<<<NN / 4, 256, 0, stream>>>(xl2, xr2, att2, bias2, offs, ssrc, out);
}

// Round 8
// 390.116 us; speedup vs baseline: 1.1981x; 1.1029x over previous
//
#include <hip/hip_runtime.h>

// ---------------- problem constants ----------------
#define NN   10000     // nodes
#define E0   160000    // raw edges
#define ET   170000    // edges + self loops
#define DIN  165       // input channels
#define KP   192       // DIN padded to 32x for MFMA K-loop
#define HID  1024      // 8 heads * 128
#define NH   8
#define MAXD 192       // max in-degree cap

// dtypes (settled r6): ALL float tensors f32, edge_index int32, OUTPUT f32.

typedef __bf16 bf16x8 __attribute__((ext_vector_type(8)));
typedef float  f32x4  __attribute__((ext_vector_type(4)));

__device__ __forceinline__ float bf2f(unsigned short u) {
    unsigned int i = ((unsigned int)u) << 16;
    return __builtin_bit_cast(float, i);
}
__device__ __forceinline__ unsigned short f2bf(float f) {
    unsigned int i = __builtin_bit_cast(unsigned int, f);
    i += 0x7fffu + ((i >> 16) & 1u);   // round-to-nearest-even
    return (unsigned short)(i >> 16);
}
__device__ __forceinline__ float fin(float x) {
    return fminf(fmaxf(x, -1e30f), 1e30f);
}
__device__ __forceinline__ int clampi(int s) {
    return min(max(s, 0), NN - 1);
}
__device__ __forceinline__ void unpack8(uint4 u, float* f) {
    f[0]=bf2f((unsigned short)(u.x)); f[1]=bf2f((unsigned short)(u.x>>16));
    f[2]=bf2f((unsigned short)(u.y)); f[3]=bf2f((unsigned short)(u.y>>16));
    f[4]=bf2f((unsigned short)(u.z)); f[5]=bf2f((unsigned short)(u.z>>16));
    f[6]=bf2f((unsigned short)(u.w)); f[7]=bf2f((unsigned short)(u.w>>16));
}

// ---------------- debug ----------------
__global__ __launch_bounds__(256) void debug_fill(float* __restrict__ out, float val) {
    int i = blockIdx.x * 256 + threadIdx.x;
    if (i < NN) out[i] = val;
}

// ---------------- BN1: column stats over x [NN, DIN] f32 ----------------
__global__ __launch_bounds__(256) void bn1_stats(const float* __restrict__ x,
                                                 float* __restrict__ colsum, float* __restrict__ colsq) {
    int r0 = blockIdx.x * 125;
    int c = threadIdx.x;
    if (c >= DIN) return;
    float acc = 0.f, sq = 0.f;
    for (int r = r0; r < r0 + 125; ++r) {
        float v = x[(size_t)r * DIN + c];
        acc += v; sq += v * v;
    }
    atomicAdd(&colsum[c], acc);
    atomicAdd(&colsq[c], sq);
}

__global__ void bn1_scale(const float* __restrict__ colsum, const float* __restrict__ colsq,
                          const float* __restrict__ gamma, const float* __restrict__ beta,
                          float* __restrict__ A, float* __restrict__ B) {
    int c = threadIdx.x;
    if (c >= DIN) return;
    float mu  = colsum[c] * (1.f / NN);
    float var = fmaxf(colsq[c] * (1.f / NN) - mu * mu, 0.f);
    float a = gamma[c] * rsqrtf(var + 1e-5f);
    A[c] = a; B[c] = beta[c] - mu * a;
}

// write normalized, K-padded input hn [NN, KP] bf16
__global__ __launch_bounds__(256) void bn1_apply(const float* __restrict__ x,
                                                 const float* __restrict__ A, const float* __restrict__ B,
                                                 unsigned short* __restrict__ hn) {
    int idx = blockIdx.x * 256 + threadIdx.x;   // NN*KP threads
    if (idx >= NN * KP) return;
    int r = idx / KP, c = idx - r * KP;
    float v = 0.f;
    if (c < DIN) v = fin(x[(size_t)r * DIN + c] * A[c] + B[c]);
    hn[idx] = f2bf(v);
}

// ---------------- transpose+pad+cvt W1: f32 [DIN,HID] -> bf16 [HID,KP] ----------------
__global__ __launch_bounds__(256) void w1_transpose(const float* __restrict__ wl,
                                                    const float* __restrict__ wr,
                                                    unsigned short* __restrict__ wlt,
                                                    unsigned short* __restrict__ wrt) {
    int idx = blockIdx.x * 256 + threadIdx.x;   // HID*KP
    if (idx >= HID * KP) return;
    int n = idx / KP, k = idx - n * KP;
    wlt[idx] = (k < DIN) ? f2bf(wl[(size_t)k * HID + n]) : (unsigned short)0;
    wrt[idx] = (k < DIN) ? f2bf(wr[(size_t)k * HID + n]) : (unsigned short)0;
}

// ---------------- GEMM1 (MFMA): hn [NN,KP] @ W [KP,HID] -> xl,xr bf16 ----------------
__global__ __launch_bounds__(256) void gemm1_kernel(
    const unsigned short* __restrict__ hn,
    const unsigned short* __restrict__ wlt,  // [HID][KP] bf16
    const unsigned short* __restrict__ wrt,
    const float* __restrict__ bl,
    const float* __restrict__ br,
    unsigned short* __restrict__ xl,
    unsigned short* __restrict__ xr) {
    const int lane = threadIdx.x & 63;
    const int wave = threadIdx.x >> 6;
    const int col  = lane & 15;
    const int q    = lane >> 4;
    const int m0 = blockIdx.x * 64 + wave * 16;
    const int n0 = blockIdx.y * 128;
    const int am = m0 + col;
    f32x4 accL[8], accR[8];
    #pragma unroll
    for (int i = 0; i < 8; ++i)
        for (int r = 0; r < 4; ++r) { accL[i][r] = 0.f; accR[i][r] = 0.f; }
    const bool aok = (am < NN);
    #pragma unroll
    for (int kt = 0; kt < 6; ++kt) {
        const int kk = kt * 32 + q * 8;
        uint4 au = make_uint4(0u, 0u, 0u, 0u);
        if (aok) au = *(const uint4*)(hn + (size_t)am * KP + kk);
        bf16x8 af = __builtin_bit_cast(bf16x8, au);
        #pragma unroll
        for (int nt = 0; nt < 8; ++nt) {
            const int nc = n0 + nt * 16 + col;
            bf16x8 bfl = __builtin_bit_cast(bf16x8, *(const uint4*)(wlt + (size_t)nc * KP + kk));
            accL[nt] = __builtin_amdgcn_mfma_f32_16x16x32_bf16(af, bfl, accL[nt], 0, 0, 0);
            bf16x8 bfr = __builtin_bit_cast(bf16x8, *(const uint4*)(wrt + (size_t)nc * KP + kk));
            accR[nt] = __builtin_amdgcn_mfma_f32_16x16x32_bf16(af, bfr, accR[nt], 0, 0, 0);
        }
    }
    #pragma unroll
    for (int nt = 0; nt < 8; ++nt) {
        const int nc = n0 + nt * 16 + col;
        const float bLv = bl[nc];
        const float bRv = br[nc];
        #pragma unroll
        for (int r = 0; r < 4; ++r) {
            const int row = m0 + q * 4 + r;
            if (row < NN) {
                xl[(size_t)row * HID + nc] = f2bf(fin(accL[nt][r] + bLv));
                xr[(size_t)row * HID + nc] = f2bf(fin(accR[nt][r] + bRv));
            }
        }
    }
}

// ---------------- edge counting-sort by dst ----------------
__global__ __launch_bounds__(256) void edge_hist(const int* __restrict__ ei, int* __restrict__ deg) {
    int e = blockIdx.x * 256 + threadIdx.x;
    if (e >= ET) return;
    int d = (e < E0) ? ei[E0 + e] : (e - E0);
    atomicAdd(&deg[clampi(d)], 1);
}

// single-block scan, 10 elems/thread, 1 barrier (r8: replaced 200-barrier version)
__global__ __launch_bounds__(1024) void scan_kernel(const int* __restrict__ deg,
                                                    int* __restrict__ offs, int* __restrict__ cur) {
    __shared__ int wsum[16];
    const int tid = threadIdx.x;
    const int base = tid * 10;          // 10240 >= NN
    int loc[10];
    int run = 0;
    #pragma unroll
    for (int j = 0; j < 10; ++j) {
        int idx = base + j;
        int v = (idx < NN) ? deg[idx] : 0;
        loc[j] = run;                    // exclusive prefix within thread
        run += v;
    }
    const int lane = tid & 63;
    const int w = tid >> 6;
    int inc = run;                       // wave-inclusive scan
    #pragma unroll
    for (int s = 1; s < 64; s <<= 1) {
        int t = __shfl_up(inc, s);
        if (lane >= s) inc += t;
    }
    if (lane == 63) wsum[w] = inc;
    __syncthreads();
    int woff = 0;
    #pragma unroll
    for (int k = 0; k < 16; ++k) woff += (k < w) ? wsum[k] : 0;
    const int toff = woff + inc - run;   // exclusive offset for this thread
    #pragma unroll
    for (int j = 0; j < 10; ++j) {
        int idx = base + j;
        if (idx < NN) { int e = toff + loc[j]; offs[idx] = e; cur[idx] = e; }
    }
    if (tid == 1023) offs[NN] = woff + inc;
}

__global__ __launch_bounds__(256) void edge_scatter(const int* __restrict__ ei,
                                                    int* __restrict__ cur, int* __restrict__ ssrc) {
    int e = blockIdx.x * 256 + threadIdx.x;
    if (e >= ET) return;
    int s, d;
    if (e < E0) { s = ei[e]; d = ei[E0 + e]; }
    else        { s = e - E0; d = e - E0; }
    int pos = atomicAdd(&cur[clampi(d)], 1);
    if (pos >= 0 && pos < ET) ssrc[pos] = clampi(s);
}

// ---------------- GAT1 fused single-gather (r8): logits+softmax+aggregate -> agg bf16 ----
// No max-subtraction: logits bounded (|p| <= ||att||*||v|| ~ 25 with BN-normed inputs),
// exp clamped at 50 for insurance; o/s ratio identical to max-shifted softmax.
// Each wave reads a gathered xl1 row ONCE, accumulates s += e^p, o += e^p*xv in regs.
// NOTE: agg aliases xr1 (row i read only by block i before sync#1; written after sync#2).
__global__ __launch_bounds__(256) void gat1_node(
    const unsigned short* __restrict__ xl1, const unsigned short* xr1,
    const float* __restrict__ att1, const float* __restrict__ bias1,
    const int* __restrict__ offs, const int* __restrict__ ssrc,
    unsigned short* agg) {
    const int i    = blockIdx.x;
    const int tid  = threadIdx.x;
    const int lane = tid & 63;
    const int wave = tid >> 6;
    __shared__ float o_lds[4][64][16];   // 16 KB (wave, lane, elem) — touched once per block
    __shared__ float s_lds[4][NH];
    __shared__ int   src_lds[MAXD];
    const int e0 = offs[i];
    const int deg = max(min(offs[i + 1] - e0, MAXD), 0);

    // per-lane channels [lane*16, lane*16+16), head = lane>>3
    float xr_r[16], att_r[16];
    {
        const uint4* xp = (const uint4*)(xr1 + (size_t)i * HID + lane * 16);
        uint4 u0 = xp[0], u1 = xp[1];
        unpack8(u0, xr_r); unpack8(u1, xr_r + 8);
        const float4* ap = (const float4*)(att1 + lane * 16);
        float4 a0 = ap[0], a1 = ap[1], a2 = ap[2], a3 = ap[3];
        att_r[0]=a0.x; att_r[1]=a0.y; att_r[2]=a0.z; att_r[3]=a0.w;
        att_r[4]=a1.x; att_r[5]=a1.y; att_r[6]=a1.z; att_r[7]=a1.w;
        att_r[8]=a2.x; att_r[9]=a2.y; att_r[10]=a2.z; att_r[11]=a2.w;
        att_r[12]=a3.x; att_r[13]=a3.y; att_r[14]=a3.z; att_r[15]=a3.w;
    }
    for (int e = tid; e < deg; e += 256) src_lds[e] = clampi(ssrc[e0 + e]);
    __syncthreads();   // #1 — all xr1 reads complete (alias safety)

    float o[16];
    #pragma unroll
    for (int j = 0; j < 16; ++j) o[j] = 0.f;
    float s = 0.f;

    for (int e = wave; e < deg; e += 4) {
        const int sidx = src_lds[e];
        const uint4* xp = (const uint4*)(xl1 + (size_t)sidx * HID + lane * 16);
        uint4 u0 = xp[0], u1 = xp[1];
        float xv[16];
        unpack8(u0, xv); unpack8(u1, xv + 8);
        float p = 0.f;
        #pragma unroll
        for (int j = 0; j < 16; ++j) {
            float v = xv[j] + xr_r[j];
            v = fmaxf(v, 0.2f * v);            // leaky_relu 0.2
            p = fmaf(att_r[j], v, p);
        }
        p += __shfl_xor(p, 1); p += __shfl_xor(p, 2); p += __shfl_xor(p, 4);
        // all 8 lanes of this head hold the full logit now
        const float a = __expf(fminf(fin(p), 50.f));
        s += a;
        #pragma unroll
        for (int j = 0; j < 16; ++j) o[j] = fmaf(a, xv[j], o[j]);
    }

    // write per-wave partials
    #pragma unroll
    for (int j = 0; j < 4; ++j)
        *(float4*)&o_lds[wave][lane][j * 4] = make_float4(o[j*4], o[j*4+1], o[j*4+2], o[j*4+3]);
    if ((lane & 7) == 0) s_lds[wave][lane >> 3] = s;
    __syncthreads();   // #2 — agg (= xr1) writes only after this

    // combine: thread t -> channels 4t..4t+3 = lane (t>>2), elems (t&3)*4..+3, head t>>5
    const int h  = tid >> 5;
    const int lo = tid >> 2;
    const int eo = (tid & 3) * 4;
    const float stot = s_lds[0][h] + s_lds[1][h] + s_lds[2][h] + s_lds[3][h];
    const float inv = 1.f / (stot + 1e-16f);
    float4 r = make_float4(0.f, 0.f, 0.f, 0.f);
    #pragma unroll
    for (int w = 0; w < 4; ++w) {
        float4 t = *(const float4*)&o_lds[w][lo][eo];
        r.x += t.x; r.y += t.y; r.z += t.z; r.w += t.w;
    }
    const float* bp = bias1 + tid * 4;
    ushort4 ov;
    ov.x = f2bf(fin(r.x * inv + bp[0]));
    ov.y = f2bf(fin(r.y * inv + bp[1]));
    ov.z = f2bf(fin(r.z * inv + bp[2]));
    ov.w = f2bf(fin(r.w * inv + bp[3]));
    *(ushort4*)(agg + (size_t)i * HID + tid * 4) = ov;
}

// ---------------- BN2 over agg [NN,HID] bf16 ----------------
__global__ __launch_bounds__(256) void bn2_stats(const unsigned short* __restrict__ agg,
                                                 float* __restrict__ colsum, float* __restrict__ colsq) {
    int r0 = blockIdx.x * 125;
    int t = threadIdx.x;
    float s0=0,s1=0,s2=0,s3=0,q0=0,q1=0,q2=0,q3=0;
    for (int r = r0; r < r0 + 125; ++r) {
        const ushort4 u = *(const ushort4*)(agg + (size_t)r * HID + t * 4);
        float v0=bf2f(u.x), v1=bf2f(u.y), v2=bf2f(u.z), v3=bf2f(u.w);
        s0+=v0; q0+=v0*v0; s1+=v1; q1+=v1*v1;
        s2+=v2; q2+=v2*v2; s3+=v3; q3+=v3*v3;
    }
    atomicAdd(&colsum[t*4+0], s0); atomicAdd(&colsq[t*4+0], q0);
    atomicAdd(&colsum[t*4+1], s1); atomicAdd(&colsq[t*4+1], q1);
    atomicAdd(&colsum[t*4+2], s2); atomicAdd(&colsq[t*4+2], q2);
    atomicAdd(&colsum[t*4+3], s3); atomicAdd(&colsq[t*4+3], q3);
}

__global__ __launch_bounds__(1024) void bn2_scale(const float* __restrict__ colsum, const float* __restrict__ colsq,
                                                  const float* __restrict__ gamma, const float* __restrict__ beta,
                                                  float* __restrict__ A, float* __restrict__ B) {
    int c = threadIdx.x;
    float mu  = colsum[c] * (1.f / NN);
    float var = fmaxf(colsq[c] * (1.f / NN) - mu * mu, 0.f);
    float a = gamma[c] * rsqrtf(var + 1e-5f);
    A[c] = a; B[c] = beta[c] - mu * a;
}

// in-place: agg(bf16) -> h2(bf16), BN affine + leaky_relu(0.01)
__global__ __launch_bounds__(256) void bn2_apply(unsigned short* __restrict__ agg,
                                                 const float* __restrict__ A, const float* __restrict__ B) {
    int idx = blockIdx.x * 256 + threadIdx.x;
    int base = idx * 4;
    int c = base & (HID - 1);
    ushort4 u = *(const ushort4*)(agg + base);
    float4 a = *(const float4*)(A + c);
    float4 b = *(const float4*)(B + c);
    float o0 = bf2f(u.x) * a.x + b.x, o1 = bf2f(u.y) * a.y + b.y;
    float o2 = bf2f(u.z) * a.z + b.z, o3 = bf2f(u.w) * a.w + b.w;
    o0 = fmaxf(o0, 0.01f * o0); o1 = fmaxf(o1, 0.01f * o1);   // leaky 0.01
    o2 = fmaxf(o2, 0.01f * o2); o3 = fmaxf(o3, 0.01f * o3);
    ushort4 o; o.x = f2bf(fin(o0)); o.y = f2bf(fin(o1)); o.z = f2bf(fin(o2)); o.w = f2bf(fin(o3));
    *(ushort4*)(agg + base) = o;
}

// ---------------- GEMM2: h2 [NN,HID] @ W2 [HID,8] (x2) -> xl2,xr2 [NN,8] f32 ----------------
__global__ __launch_bounds__(256) void gemm2_kernel(
    const unsigned short* __restrict__ h2,
    const float* __restrict__ wl2, const float* __restrict__ bl2,
    const float* __restrict__ wr2, const float* __restrict__ br2,
    float* __restrict__ xl2, float* __restrict__ xr2) {
    const int lane = threadIdx.x & 63;
    const int wave = threadIdx.x >> 6;
    const int row = blockIdx.x * 4 + wave;
    float accL[8] = {0,0,0,0,0,0,0,0};
    float accR[8] = {0,0,0,0,0,0,0,0};
    const uint4* hp = (const uint4*)(h2 + (size_t)row * HID + lane * 16);
    uint4 u0 = hp[0], u1 = hp[1];
    float hv[16];
    unpack8(u0, hv); unpack8(u1, hv + 8);
    #pragma unroll
    for (int j = 0; j < 16; ++j) {
        const int c = lane * 16 + j;
        const float4 wla = *(const float4*)(wl2 + c * 8);
        const float4 wlb = *(const float4*)(wl2 + c * 8 + 4);
        const float4 wra = *(const float4*)(wr2 + c * 8);
        const float4 wrb = *(const float4*)(wr2 + c * 8 + 4);
        const float hvj = hv[j];
        accL[0] = fmaf(hvj, wla.x, accL[0]); accL[1] = fmaf(hvj, wla.y, accL[1]);
        accL[2] = fmaf(hvj, wla.z, accL[2]); accL[3] = fmaf(hvj, wla.w, accL[3]);
        accL[4] = fmaf(hvj, wlb.x, accL[4]); accL[5] = fmaf(hvj, wlb.y, accL[5]);
        accL[6] = fmaf(hvj, wlb.z, accL[6]); accL[7] = fmaf(hvj, wlb.w, accL[7]);
        accR[0] = fmaf(hvj, wra.x, accR[0]); accR[1] = fmaf(hvj, wra.y, accR[1]);
        accR[2] = fmaf(hvj, wra.z, accR[2]); accR[3] = fmaf(hvj, wra.w, accR[3]);
        accR[4] = fmaf(hvj, wrb.x, accR[4]); accR[5] = fmaf(hvj, wrb.y, accR[5]);
        accR[6] = fmaf(hvj, wrb.z, accR[6]); accR[7] = fmaf(hvj, wrb.w, accR[7]);
    }
    #pragma unroll
    for (int k = 0; k < 8; ++k) {
        for (int m = 1; m < 64; m <<= 1) {
            accL[k] += __shfl_xor(accL[k], m);
            accR[k] += __shfl_xor(accR[k], m);
        }
    }
    if (lane == 0) {
        #pragma unroll
        for (int k = 0; k < 8; ++k) {
            xl2[row * 8 + k] = fin(accL[k] + bl2[k]);
            xr2[row * 8 + k] = fin(accR[k] + br2[k]);
        }
    }
}

// ---------------- GAT2 per-node (wave per node), mean over heads -> f32 out ----------------
__global__ __launch_bounds__(256) void gat2_node(
    const float* __restrict__ xl2, const float* __restrict__ xr2,
    const float* __restrict__ att2, const float* __restrict__ bias2,
    const int* __restrict__ offs, const int* __restrict__ ssrc,
    float* __restrict__ out) {
    const int lane = threadIdx.x & 63;
    const int wave = threadIdx.x >> 6;
    const int i = blockIdx.x * 4 + wave;
    const int h = lane & 7, slot = lane >> 3;
    const int e0 = offs[i];
    const int e1 = max(offs[i + 1], e0);
    const float xr_h = xr2[i * 8 + h];
    const float att_h = att2[h];
    float m = -1e30f;
    for (int eb = e0; eb < e1; eb += 8) {
        int e = eb + slot;
        float lg = -1e30f;
        if (e < e1) {
            float v = xl2[clampi(ssrc[e]) * 8 + h] + xr_h;
            v = fmaxf(v, 0.2f * v);
            lg = fin(att_h * v);
        }
        m = fmaxf(m, lg);
    }
    m = fmaxf(m, __shfl_xor(m, 8)); m = fmaxf(m, __shfl_xor(m, 16)); m = fmaxf(m, __shfl_xor(m, 32));
    float ssum = 0.f, wsum = 0.f;
    for (int eb = e0; eb < e1; eb += 8) {
        int e = eb + slot;
        if (e < e1) {
            float xlv = xl2[clampi(ssrc[e]) * 8 + h];
            float v = xlv + xr_h;
            v = fmaxf(v, 0.2f * v);
            float a = __expf(fminf(fin(att_h * v) - m, 0.f));
            ssum += a; wsum += a * xlv;
        }
    }
    ssum += __shfl_xor(ssum, 8); ssum += __shfl_xor(ssum, 16); ssum += __shfl_xor(ssum, 32);
    wsum += __shfl_xor(wsum, 8); wsum += __shfl_xor(wsum, 16); wsum += __shfl_xor(wsum, 32);
    float v = fin(wsum / (ssum + 1e-16f));
    v += __shfl_xor(v, 1); v += __shfl_xor(v, 2); v += __shfl_xor(v, 4);
    if (lane == 0) out[i] = fin(v * 0.125f + bias2[0]);
}

// ---------------- launch ----------------
extern "C" void kernel_launch(void* const* d_in, const int* in_sizes, int n_in,
                              void* d_out, int out_size, void* d_ws, size_t ws_size,
                              hipStream_t stream) {
    float* out = (float*)d_out;   // reference output dtype is float32

    static const int expected[18] = {
        NN * DIN, DIN, DIN, DIN * HID, HID, DIN * HID, HID, HID, HID,
        HID, HID, HID * NH, NH, HID * NH, NH, NH, 1, 2 * E0
    };
    if (n_in != 18) {
        debug_fill<<<(NN + 255) / 256, 256, 0, stream>>>(out, 8192.f + 64.f * (float)n_in);
        return;
    }
    for (int i = 0; i < 18; ++i) {
        if (in_sizes[i] != expected[i]) {
            debug_fill<<<(NN + 255) / 256, 256, 0, stream>>>(out, 4096.f + 32.f * (float)i);
            return;
        }
    }

    const float* x      = (const float*)d_in[0];
    const float* gamma1 = (const float*)d_in[1];
    const float* beta1  = (const float*)d_in[2];
    const float* Wl1    = (const float*)d_in[3];
    const float* bl1    = (const float*)d_in[4];
    const float* Wr1    = (const float*)d_in[5];
    const float* br1    = (const float*)d_in[6];
    const float* att1   = (const float*)d_in[7];
    const float* bias1  = (const float*)d_in[8];
    const float* gamma2 = (const float*)d_in[9];
    const float* beta2  = (const float*)d_in[10];
    const float* Wl2    = (const float*)d_in[11];
    const float* bl2    = (const float*)d_in[12];
    const float* Wr2    = (const float*)d_in[13];
    const float* br2    = (const float*)d_in[14];
    const float* att2   = (const float*)d_in[15];
    const float* bias2  = (const float*)d_in[16];
    const int*   ei     = (const int*)d_in[17];

    char* p = (char*)d_ws;
    auto alloc = [&](size_t bytes) -> void* {
        void* r = (void*)p;
        p += (bytes + 255) & ~(size_t)255;
        return r;
    };
    unsigned short* xl1  = (unsigned short*)alloc((size_t)NN * HID * 2);  // 20.48 MB
    unsigned short* xr1  = (unsigned short*)alloc((size_t)NN * HID * 2);  // 20.48 MB
    unsigned short* agg  = xr1;                                           // ALIAS (see gat1_node)
    unsigned short* hn   = (unsigned short*)alloc((size_t)NN * KP * 2);   // 3.84 MB
    unsigned short* wlt  = (unsigned short*)alloc((size_t)HID * KP * 2);  // 0.39 MB
    unsigned short* wrt  = (unsigned short*)alloc((size_t)HID * KP * 2);  // 0.39 MB
    float*          xl2  = (float*)alloc((size_t)NN * 8 * 4);
    float*          xr2  = (float*)alloc((size_t)NN * 8 * 4);
    float*          A1   = (float*)alloc(DIN * 4);
    float*          B1   = (float*)alloc(DIN * 4);
    float*          A2   = (float*)alloc(HID * 4);
    float*          B2   = (float*)alloc(HID * 4);
    int*            offs = (int*)alloc((NN + 1) * 4);
    int*            cur  = (int*)alloc(NN * 4);
    int*            ssrc = (int*)alloc(ET * 4);
    char* zbase = p;
    float* colsum1 = (float*)alloc(DIN * 4);
    float* colsq1  = (float*)alloc(DIN * 4);
    float* colsum2 = (float*)alloc(HID * 4);
    float* colsq2  = (float*)alloc(HID * 4);
    int*   deg     = (int*)alloc(NN * 4);
    size_t zlen = (size_t)(p - zbase);
    hipMemsetAsync(zbase, 0, zlen, stream);

    // BN1 -> hn [NN,KP] bf16
    bn1_stats<<<80, 256, 0, stream>>>(x, colsum1, colsq1);
    bn1_scale<<<1, 256, 0, stream>>>(colsum1, colsq1, gamma1, beta1, A1, B1);
    bn1_apply<<<(NN * KP + 255) / 256, 256, 0, stream>>>(x, A1, B1, hn);
    // W1 transpose+pad+cvt (f32 -> bf16 [HID,KP])
    w1_transpose<<<(HID * KP + 255) / 256, 256, 0, stream>>>(Wl1, Wr1, wlt, wrt);
    // GEMM1 (MFMA bf16) -> xl1, xr1
    gemm1_kernel<<<dim3((NN + 63) / 64, HID / 128), 256, 0, stream>>>(hn, wlt, wrt, bl1, br1, xl1, xr1);
    // edge sort by dst
    edge_hist<<<(ET + 255) / 256, 256, 0, stream>>>(ei, deg);
    scan_kernel<<<1, 1024, 0, stream>>>(deg, offs, cur);
    edge_scatter<<<(ET + 255) / 256, 256, 0, stream>>>(ei, cur, ssrc);
    // GAT1 fused single-gather -> agg (bf16, +bias1) ; agg aliases xr1
    gat1_node<<<NN, 256, 0, stream>>>(xl1, xr1, att1, bias1, offs, ssrc, agg);
    // BN2 + leaky(0.01) in-place on agg -> h2
    bn2_stats<<<80, 256, 0, stream>>>(agg, colsum2, colsq2);
    bn2_scale<<<1, 1024, 0, stream>>>(colsum2, colsq2, gamma2, beta2, A2, B2);
    bn2_apply<<<(NN * HID / 4 + 255) / 256, 256, 0, stream>>>(agg, A2, B2);
    // GEMM2 -> xl2, xr2
    gemm2_kernel<<<NN / 4, 256, 0, stream>>>(agg, Wl2, bl2, Wr2, br2, xl2, xr2);
    // GAT2 -> out (f32)
    gat2_node<<<NN / 4, 256, 0, stream>>>(xl2, xr2, att2, bias2, offs, ssrc, out);
}

// Round 9
// 347.636 us; speedup vs baseline: 1.3445x; 1.1222x over previous
//
#include <hip/hip_runtime.h>

// ---------------- problem constants ----------------
#define NN   10000     // nodes
#define E0   160000    // raw edges
#define ET   170000    // edges + self loops
#define DIN  165       // input channels
#define KP   192       // DIN padded to 32x for MFMA K-loop
#define HID  1024      // 8 heads * 128
#define NH   8
#define MAXD 192       // max in-degree cap
#define BP   200       // LDS row pitch for B-tile (192 + 8: 2-way-conflict-free, 16B aligned rows)

// dtypes (settled r6): ALL float tensors f32, edge_index int32, OUTPUT f32.

typedef __bf16 bf16x8 __attribute__((ext_vector_type(8)));
typedef float  f32x4  __attribute__((ext_vector_type(4)));

__device__ __forceinline__ float bf2f(unsigned short u) {
    unsigned int i = ((unsigned int)u) << 16;
    return __builtin_bit_cast(float, i);
}
__device__ __forceinline__ unsigned short f2bf(float f) {
    unsigned int i = __builtin_bit_cast(unsigned int, f);
    i += 0x7fffu + ((i >> 16) & 1u);   // round-to-nearest-even
    return (unsigned short)(i >> 16);
}
__device__ __forceinline__ float fin(float x) {
    return fminf(fmaxf(x, -1e30f), 1e30f);
}
__device__ __forceinline__ int clampi(int s) {
    return min(max(s, 0), NN - 1);
}
__device__ __forceinline__ void unpack8(uint4 u, float* f) {
    f[0]=bf2f((unsigned short)(u.x)); f[1]=bf2f((unsigned short)(u.x>>16));
    f[2]=bf2f((unsigned short)(u.y)); f[3]=bf2f((unsigned short)(u.y>>16));
    f[4]=bf2f((unsigned short)(u.z)); f[5]=bf2f((unsigned short)(u.z>>16));
    f[6]=bf2f((unsigned short)(u.w)); f[7]=bf2f((unsigned short)(u.w>>16));
}

// ---------------- debug ----------------
__global__ __launch_bounds__(256) void debug_fill(float* __restrict__ out, float val) {
    int i = blockIdx.x * 256 + threadIdx.x;
    if (i < NN) out[i] = val;
}

// ---------------- BN1: column stats over x [NN, DIN] f32 ----------------
__global__ __launch_bounds__(256) void bn1_stats(const float* __restrict__ x,
                                                 float* __restrict__ colsum, float* __restrict__ colsq) {
    int r0 = blockIdx.x * 125;
    int c = threadIdx.x;
    if (c >= DIN) return;
    float acc = 0.f, sq = 0.f;
    for (int r = r0; r < r0 + 125; ++r) {
        float v = x[(size_t)r * DIN + c];
        acc += v; sq += v * v;
    }
    atomicAdd(&colsum[c], acc);
    atomicAdd(&colsq[c], sq);
}

__global__ void bn1_scale(const float* __restrict__ colsum, const float* __restrict__ colsq,
                          const float* __restrict__ gamma, const float* __restrict__ beta,
                          float* __restrict__ A, float* __restrict__ B) {
    int c = threadIdx.x;
    if (c >= DIN) return;
    float mu  = colsum[c] * (1.f / NN);
    float var = fmaxf(colsq[c] * (1.f / NN) - mu * mu, 0.f);
    float a = gamma[c] * rsqrtf(var + 1e-5f);
    A[c] = a; B[c] = beta[c] - mu * a;
}

// write normalized, K-padded input hn [NN, KP] bf16
__global__ __launch_bounds__(256) void bn1_apply(const float* __restrict__ x,
                                                 const float* __restrict__ A, const float* __restrict__ B,
                                                 unsigned short* __restrict__ hn) {
    int idx = blockIdx.x * 256 + threadIdx.x;   // NN*KP threads
    if (idx >= NN * KP) return;
    int r = idx / KP, c = idx - r * KP;
    float v = 0.f;
    if (c < DIN) v = fin(x[(size_t)r * DIN + c] * A[c] + B[c]);
    hn[idx] = f2bf(v);
}

// ---------------- transpose+pad+cvt W1: f32 [DIN,HID] -> bf16 [HID,KP] ----------------
__global__ __launch_bounds__(256) void w1_transpose(const float* __restrict__ wl,
                                                    const float* __restrict__ wr,
                                                    unsigned short* __restrict__ wlt,
                                                    unsigned short* __restrict__ wrt) {
    int idx = blockIdx.x * 256 + threadIdx.x;   // HID*KP
    if (idx >= HID * KP) return;
    int n = idx / KP, k = idx - n * KP;
    wlt[idx] = (k < DIN) ? f2bf(wl[(size_t)k * HID + n]) : (unsigned short)0;
    wrt[idx] = (k < DIN) ? f2bf(wr[(size_t)k * HID + n]) : (unsigned short)0;
}

// ---------------- GEMM1 (MFMA, LDS-staged B): hn [NN,KP] @ W [KP,HID] -> xl,xr bf16 ------
// r9: B-tile (64 cols x 192 K) staged in LDS once per block; 1 ds_read_b128 feeds 2 MFMAs
// (two m-frags per wave). Was: direct-from-global B loads -> latency-bound (85us, 3% MfmaUtil).
// Grid: (m-tiles=79, n-tiles=16, z=L/R). Tile M=128 (4 waves x 2x16), N=64.
__global__ __launch_bounds__(256) void gemm1_kernel(
    const unsigned short* __restrict__ hn,
    const unsigned short* __restrict__ wlt,  // [HID][KP] bf16
    const unsigned short* __restrict__ wrt,
    const float* __restrict__ bl,
    const float* __restrict__ br,
    unsigned short* __restrict__ xl,
    unsigned short* __restrict__ xr) {
    const unsigned short* wt = blockIdx.z ? wrt : wlt;
    const float* bias        = blockIdx.z ? br  : bl;
    unsigned short* xout     = blockIdx.z ? xr  : xl;

    __shared__ unsigned short bs[64 * BP];   // 25.6 KB
    const int tid  = threadIdx.x;
    const int lane = tid & 63;
    const int wave = tid >> 6;
    const int col  = lane & 15;
    const int q    = lane >> 4;
    const int n0   = blockIdx.y * 64;

    // stage B-tile: 64 rows x 192 elems, uint2 (4 bf16) granules, coalesced
    for (int idx = tid; idx < 64 * 48; idx += 256) {
        int r = idx / 48, c = idx - r * 48;
        uint2 v = *(const uint2*)(wt + (size_t)(n0 + r) * KP + c * 4);
        *(uint2*)&bs[r * BP + c * 4] = v;
    }
    __syncthreads();

    const int mbase = blockIdx.x * 128 + wave * 32;
    const int am0 = mbase + col;
    const int am1 = am0 + 16;
    const bool aok0 = (am0 < NN), aok1 = (am1 < NN);

    f32x4 acc[2][4];
    #pragma unroll
    for (int m = 0; m < 2; ++m)
        for (int nt = 0; nt < 4; ++nt)
            for (int r = 0; r < 4; ++r) acc[m][nt][r] = 0.f;

    #pragma unroll
    for (int kt = 0; kt < 6; ++kt) {
        const int kk = kt * 32 + q * 8;
        uint4 a0u = make_uint4(0u,0u,0u,0u), a1u = make_uint4(0u,0u,0u,0u);
        if (aok0) a0u = *(const uint4*)(hn + (size_t)am0 * KP + kk);
        if (aok1) a1u = *(const uint4*)(hn + (size_t)am1 * KP + kk);
        bf16x8 a0 = __builtin_bit_cast(bf16x8, a0u);
        bf16x8 a1 = __builtin_bit_cast(bf16x8, a1u);
        #pragma unroll
        for (int nt = 0; nt < 4; ++nt) {
            bf16x8 bf = __builtin_bit_cast(bf16x8, *(const uint4*)&bs[(nt * 16 + col) * BP + kk]);
            acc[0][nt] = __builtin_amdgcn_mfma_f32_16x16x32_bf16(a0, bf, acc[0][nt], 0, 0, 0);
            acc[1][nt] = __builtin_amdgcn_mfma_f32_16x16x32_bf16(a1, bf, acc[1][nt], 0, 0, 0);
        }
    }

    #pragma unroll
    for (int nt = 0; nt < 4; ++nt) {
        const int nc = n0 + nt * 16 + col;
        const float bv = bias[nc];
        #pragma unroll
        for (int m = 0; m < 2; ++m) {
            #pragma unroll
            for (int r = 0; r < 4; ++r) {
                const int row = mbase + m * 16 + q * 4 + r;
                if (row < NN)
                    xout[(size_t)row * HID + nc] = f2bf(fin(acc[m][nt][r] + bv));
            }
        }
    }
}

// ---------------- edge counting-sort by dst ----------------
__global__ __launch_bounds__(256) void edge_hist(const int* __restrict__ ei, int* __restrict__ deg) {
    int e = blockIdx.x * 256 + threadIdx.x;
    if (e >= ET) return;
    int d = (e < E0) ? ei[E0 + e] : (e - E0);
    atomicAdd(&deg[clampi(d)], 1);
}

// single-block scan, 10 elems/thread, 1 barrier
__global__ __launch_bounds__(1024) void scan_kernel(const int* __restrict__ deg,
                                                    int* __restrict__ offs, int* __restrict__ cur) {
    __shared__ int wsum[16];
    const int tid = threadIdx.x;
    const int base = tid * 10;          // 10240 >= NN
    int loc[10];
    int run = 0;
    #pragma unroll
    for (int j = 0; j < 10; ++j) {
        int idx = base + j;
        int v = (idx < NN) ? deg[idx] : 0;
        loc[j] = run;
        run += v;
    }
    const int lane = tid & 63;
    const int w = tid >> 6;
    int inc = run;
    #pragma unroll
    for (int s = 1; s < 64; s <<= 1) {
        int t = __shfl_up(inc, s);
        if (lane >= s) inc += t;
    }
    if (lane == 63) wsum[w] = inc;
    __syncthreads();
    int woff = 0;
    #pragma unroll
    for (int k = 0; k < 16; ++k) woff += (k < w) ? wsum[k] : 0;
    const int toff = woff + inc - run;
    #pragma unroll
    for (int j = 0; j < 10; ++j) {
        int idx = base + j;
        if (idx < NN) { int e = toff + loc[j]; offs[idx] = e; cur[idx] = e; }
    }
    if (tid == 1023) offs[NN] = woff + inc;
}

__global__ __launch_bounds__(256) void edge_scatter(const int* __restrict__ ei,
                                                    int* __restrict__ cur, int* __restrict__ ssrc) {
    int e = blockIdx.x * 256 + threadIdx.x;
    if (e >= ET) return;
    int s, d;
    if (e < E0) { s = ei[e]; d = ei[E0 + e]; }
    else        { s = e - E0; d = e - E0; }
    int pos = atomicAdd(&cur[clampi(d)], 1);
    if (pos >= 0 && pos < ET) ssrc[pos] = clampi(s);
}

// ---------------- GAT1 fused single-gather: logits+softmax+aggregate -> agg bf16 ----
// No max-subtraction (logits bounded, exp clamped at 50; o/s ratio identical).
// NOTE: agg aliases xr1 (row i read only by block i before sync#1; written after sync#2).
__global__ __launch_bounds__(256) void gat1_node(
    const unsigned short* __restrict__ xl1, const unsigned short* xr1,
    const float* __restrict__ att1, const float* __restrict__ bias1,
    const int* __restrict__ offs, const int* __restrict__ ssrc,
    unsigned short* agg) {
    const int i    = blockIdx.x;
    const int tid  = threadIdx.x;
    const int lane = tid & 63;
    const int wave = tid >> 6;
    __shared__ float o_lds[4][64][16];   // 16 KB
    __shared__ float s_lds[4][NH];
    __shared__ int   src_lds[MAXD];
    const int e0 = offs[i];
    const int deg = max(min(offs[i + 1] - e0, MAXD), 0);

    float xr_r[16], att_r[16];
    {
        const uint4* xp = (const uint4*)(xr1 + (size_t)i * HID + lane * 16);
        uint4 u0 = xp[0], u1 = xp[1];
        unpack8(u0, xr_r); unpack8(u1, xr_r + 8);
        const float4* ap = (const float4*)(att1 + lane * 16);
        float4 a0 = ap[0], a1 = ap[1], a2 = ap[2], a3 = ap[3];
        att_r[0]=a0.x; att_r[1]=a0.y; att_r[2]=a0.z; att_r[3]=a0.w;
        att_r[4]=a1.x; att_r[5]=a1.y; att_r[6]=a1.z; att_r[7]=a1.w;
        att_r[8]=a2.x; att_r[9]=a2.y; att_r[10]=a2.z; att_r[11]=a2.w;
        att_r[12]=a3.x; att_r[13]=a3.y; att_r[14]=a3.z; att_r[15]=a3.w;
    }
    for (int e = tid; e < deg; e += 256) src_lds[e] = clampi(ssrc[e0 + e]);
    __syncthreads();   // #1 — all xr1 reads complete (alias safety)

    float o[16];
    #pragma unroll
    for (int j = 0; j < 16; ++j) o[j] = 0.f;
    float s = 0.f;

    for (int e = wave; e < deg; e += 4) {
        const int sidx = src_lds[e];
        const uint4* xp = (const uint4*)(xl1 + (size_t)sidx * HID + lane * 16);
        uint4 u0 = xp[0], u1 = xp[1];
        float xv[16];
        unpack8(u0, xv); unpack8(u1, xv + 8);
        float p = 0.f;
        #pragma unroll
        for (int j = 0; j < 16; ++j) {
            float v = xv[j] + xr_r[j];
            v = fmaxf(v, 0.2f * v);            // leaky_relu 0.2
            p = fmaf(att_r[j], v, p);
        }
        p += __shfl_xor(p, 1); p += __shfl_xor(p, 2); p += __shfl_xor(p, 4);
        const float a = __expf(fminf(fin(p), 50.f));
        s += a;
        #pragma unroll
        for (int j = 0; j < 16; ++j) o[j] = fmaf(a, xv[j], o[j]);
    }

    #pragma unroll
    for (int j = 0; j < 4; ++j)
        *(float4*)&o_lds[wave][lane][j * 4] = make_float4(o[j*4], o[j*4+1], o[j*4+2], o[j*4+3]);
    if ((lane & 7) == 0) s_lds[wave][lane >> 3] = s;
    __syncthreads();   // #2 — agg (= xr1) writes only after this

    const int h  = tid >> 5;
    const int lo = tid >> 2;
    const int eo = (tid & 3) * 4;
    const float stot = s_lds[0][h] + s_lds[1][h] + s_lds[2][h] + s_lds[3][h];
    const float inv = 1.f / (stot + 1e-16f);
    float4 r = make_float4(0.f, 0.f, 0.f, 0.f);
    #pragma unroll
    for (int w = 0; w < 4; ++w) {
        float4 t = *(const float4*)&o_lds[w][lo][eo];
        r.x += t.x; r.y += t.y; r.z += t.z; r.w += t.w;
    }
    const float* bp = bias1 + tid * 4;
    ushort4 ov;
    ov.x = f2bf(fin(r.x * inv + bp[0]));
    ov.y = f2bf(fin(r.y * inv + bp[1]));
    ov.z = f2bf(fin(r.z * inv + bp[2]));
    ov.w = f2bf(fin(r.w * inv + bp[3]));
    *(ushort4*)(agg + (size_t)i * HID + tid * 4) = ov;
}

// ---------------- BN2 over agg [NN,HID] bf16 ----------------
__global__ __launch_bounds__(256) void bn2_stats(const unsigned short* __restrict__ agg,
                                                 float* __restrict__ colsum, float* __restrict__ colsq) {
    int r0 = blockIdx.x * 125;
    int t = threadIdx.x;
    float s0=0,s1=0,s2=0,s3=0,q0=0,q1=0,q2=0,q3=0;
    for (int r = r0; r < r0 + 125; ++r) {
        const ushort4 u = *(const ushort4*)(agg + (size_t)r * HID + t * 4);
        float v0=bf2f(u.x), v1=bf2f(u.y), v2=bf2f(u.z), v3=bf2f(u.w);
        s0+=v0; q0+=v0*v0; s1+=v1; q1+=v1*v1;
        s2+=v2; q2+=v2*v2; s3+=v3; q3+=v3*v3;
    }
    atomicAdd(&colsum[t*4+0], s0); atomicAdd(&colsq[t*4+0], q0);
    atomicAdd(&colsum[t*4+1], s1); atomicAdd(&colsq[t*4+1], q1);
    atomicAdd(&colsum[t*4+2], s2); atomicAdd(&colsq[t*4+2], q2);
    atomicAdd(&colsum[t*4+3], s3); atomicAdd(&colsq[t*4+3], q3);
}

__global__ __launch_bounds__(1024) void bn2_scale(const float* __restrict__ colsum, const float* __restrict__ colsq,
                                                  const float* __restrict__ gamma, const float* __restrict__ beta,
                                                  float* __restrict__ A, float* __restrict__ B) {
    int c = threadIdx.x;
    float mu  = colsum[c] * (1.f / NN);
    float var = fmaxf(colsq[c] * (1.f / NN) - mu * mu, 0.f);
    float a = gamma[c] * rsqrtf(var + 1e-5f);
    A[c] = a; B[c] = beta[c] - mu * a;
}

// in-place: agg(bf16) -> h2(bf16), BN affine + leaky_relu(0.01)
__global__ __launch_bounds__(256) void bn2_apply(unsigned short* __restrict__ agg,
                                                 const float* __restrict__ A, const float* __restrict__ B) {
    int idx = blockIdx.x * 256 + threadIdx.x;
    int base = idx * 4;
    int c = base & (HID - 1);
    ushort4 u = *(const ushort4*)(agg + base);
    float4 a = *(const float4*)(A + c);
    float4 b = *(const float4*)(B + c);
    float o0 = bf2f(u.x) * a.x + b.x, o1 = bf2f(u.y) * a.y + b.y;
    float o2 = bf2f(u.z) * a.z + b.z, o3 = bf2f(u.w) * a.w + b.w;
    o0 = fmaxf(o0, 0.01f * o0); o1 = fmaxf(o1, 0.01f * o1);   // leaky 0.01
    o2 = fmaxf(o2, 0.01f * o2); o3 = fmaxf(o3, 0.01f * o3);
    ushort4 o; o.x = f2bf(fin(o0)); o.y = f2bf(fin(o1)); o.z = f2bf(fin(o2)); o.w = f2bf(fin(o3));
    *(ushort4*)(agg + base) = o;
}

// ---------------- GEMM2: h2 [NN,HID] @ W2 [HID,8] (x2) -> xl2,xr2 [NN,8] f32 ----------------
__global__ __launch_bounds__(256) void gemm2_kernel(
    const unsigned short* __restrict__ h2,
    const float* __restrict__ wl2, const float* __restrict__ bl2,
    const float* __restrict__ wr2, const float* __restrict__ br2,
    float* __restrict__ xl2, float* __restrict__ xr2) {
    const int lane = threadIdx.x & 63;
    const int wave = threadIdx.x >> 6;
    const int row = blockIdx.x * 4 + wave;
    float accL[8] = {0,0,0,0,0,0,0,0};
    float accR[8] = {0,0,0,0,0,0,0,0};
    const uint4* hp = (const uint4*)(h2 + (size_t)row * HID + lane * 16);
    uint4 u0 = hp[0], u1 = hp[1];
    float hv[16];
    unpack8(u0, hv); unpack8(u1, hv + 8);
    #pragma unroll
    for (int j = 0; j < 16; ++j) {
        const int c = lane * 16 + j;
        const float4 wla = *(const float4*)(wl2 + c * 8);
        const float4 wlb = *(const float4*)(wl2 + c * 8 + 4);
        const float4 wra = *(const float4*)(wr2 + c * 8);
        const float4 wrb = *(const float4*)(wr2 + c * 8 + 4);
        const float hvj = hv[j];
        accL[0] = fmaf(hvj, wla.x, accL[0]); accL[1] = fmaf(hvj, wla.y, accL[1]);
        accL[2] = fmaf(hvj, wla.z, accL[2]); accL[3] = fmaf(hvj, wla.w, accL[3]);
        accL[4] = fmaf(hvj, wlb.x, accL[4]); accL[5] = fmaf(hvj, wlb.y, accL[5]);
        accL[6] = fmaf(hvj, wlb.z, accL[6]); accL[7] = fmaf(hvj, wlb.w, accL[7]);
        accR[0] = fmaf(hvj, wra.x, accR[0]); accR[1] = fmaf(hvj, wra.y, accR[1]);
        accR[2] = fmaf(hvj, wra.z, accR[2]); accR[3] = fmaf(hvj, wra.w, accR[3]);
        accR[4] = fmaf(hvj, wrb.x, accR[4]); accR[5] = fmaf(hvj, wrb.y, accR[5]);
        accR[6] = fmaf(hvj, wrb.z, accR[6]); accR[7] = fmaf(hvj, wrb.w, accR[7]);
    }
    #pragma unroll
    for (int k = 0; k < 8; ++k) {
        for (int m = 1; m < 64; m <<= 1) {
            accL[k] += __shfl_xor(accL[k], m);
            accR[k] += __shfl_xor(accR[k], m);
        }
    }
    if (lane == 0) {
        #pragma unroll
        for (int k = 0; k < 8; ++k) {
            xl2[row * 8 + k] = fin(accL[k] + bl2[k]);
            xr2[row * 8 + k] = fin(accR[k] + br2[k]);
        }
    }
}

// ---------------- GAT2 per-node (wave per node), mean over heads -> f32 out ----------------
__global__ __launch_bounds__(256) void gat2_node(
    const float* __restrict__ xl2, const float* __restrict__ xr2,
    const float* __restrict__ att2, const float* __restrict__ bias2,
    const int* __restrict__ offs, const int* __restrict__ ssrc,
    float* __restrict__ out) {
    const int lane = threadIdx.x & 63;
    const int wave = threadIdx.x >> 6;
    const int i = blockIdx.x * 4 + wave;
    const int h = lane & 7, slot = lane >> 3;
    const int e0 = offs[i];
    const int e1 = max(offs[i + 1], e0);
    const float xr_h = xr2[i * 8 + h];
    const float att_h = att2[h];
    float m = -1e30f;
    for (int eb = e0; eb < e1; eb += 8) {
        int e = eb + slot;
        float lg = -1e30f;
        if (e < e1) {
            float v = xl2[clampi(ssrc[e]) * 8 + h] + xr_h;
            v = fmaxf(v, 0.2f * v);
            lg = fin(att_h * v);
        }
        m = fmaxf(m, lg);
    }
    m = fmaxf(m, __shfl_xor(m, 8)); m = fmaxf(m, __shfl_xor(m, 16)); m = fmaxf(m, __shfl_xor(m, 32));
    float ssum = 0.f, wsum = 0.f;
    for (int eb = e0; eb < e1; eb += 8) {
        int e = eb + slot;
        if (e < e1) {
            float xlv = xl2[clampi(ssrc[e]) * 8 + h];
            float v = xlv + xr_h;
            v = fmaxf(v, 0.2f * v);
            float a = __expf(fminf(fin(att_h * v) - m, 0.f));
            ssum += a; wsum += a * xlv;
        }
    }
    ssum += __shfl_xor(ssum, 8); ssum += __shfl_xor(ssum, 16); ssum += __shfl_xor(ssum, 32);
    wsum += __shfl_xor(wsum, 8); wsum += __shfl_xor(wsum, 16); wsum += __shfl_xor(wsum, 32);
    float v = fin(wsum / (ssum + 1e-16f));
    v += __shfl_xor(v, 1); v += __shfl_xor(v, 2); v += __shfl_xor(v, 4);
    if (lane == 0) out[i] = fin(v * 0.125f + bias2[0]);
}

// ---------------- launch ----------------
extern "C" void kernel_launch(void* const* d_in, const int* in_sizes, int n_in,
                              void* d_out, int out_size, void* d_ws, size_t ws_size,
                              hipStream_t stream) {
    float* out = (float*)d_out;   // reference output dtype is float32

    static const int expected[18] = {
        NN * DIN, DIN, DIN, DIN * HID, HID, DIN * HID, HID, HID, HID,
        HID, HID, HID * NH, NH, HID * NH, NH, NH, 1, 2 * E0
    };
    if (n_in != 18) {
        debug_fill<<<(NN + 255) / 256, 256, 0, stream>>>(out, 8192.f + 64.f * (float)n_in);
        return;
    }
    for (int i = 0; i < 18; ++i) {
        if (in_sizes[i] != expected[i]) {
            debug_fill<<<(NN + 255) / 256, 256, 0, stream>>>(out, 4096.f + 32.f * (float)i);
            return;
        }
    }

    const float* x      = (const float*)d_in[0];
    const float* gamma1 = (const float*)d_in[1];
    const float* beta1  = (const float*)d_in[2];
    const float* Wl1    = (const float*)d_in[3];
    const float* bl1    = (const float*)d_in[4];
    const float* Wr1    = (const float*)d_in[5];
    const float* br1    = (const float*)d_in[6];
    const float* att1   = (const float*)d_in[7];
    const float* bias1  = (const float*)d_in[8];
    const float* gamma2 = (const float*)d_in[9];
    const float* beta2  = (const float*)d_in[10];
    const float* Wl2    = (const float*)d_in[11];
    const float* bl2    = (const float*)d_in[12];
    const float* Wr2    = (const float*)d_in[13];
    const float* br2    = (const float*)d_in[14];
    const float* att2   = (const float*)d_in[15];
    const float* bias2  = (const float*)d_in[16];
    const int*   ei     = (const int*)d_in[17];

    char* p = (char*)d_ws;
    auto alloc = [&](size_t bytes) -> void* {
        void* r = (void*)p;
        p += (bytes + 255) & ~(size_t)255;
        return r;
    };
    unsigned short* xl1  = (unsigned short*)alloc((size_t)NN * HID * 2);  // 20.48 MB
    unsigned short* xr1  = (unsigned short*)alloc((size_t)NN * HID * 2);  // 20.48 MB
    unsigned short* agg  = xr1;                                           // ALIAS (see gat1_node)
    unsigned short* hn   = (unsigned short*)alloc((size_t)NN * KP * 2);   // 3.84 MB
    unsigned short* wlt  = (unsigned short*)alloc((size_t)HID * KP * 2);  // 0.39 MB
    unsigned short* wrt  = (unsigned short*)alloc((size_t)HID * KP * 2);  // 0.39 MB
    float*          xl2  = (float*)alloc((size_t)NN * 8 * 4);
    float*          xr2  = (float*)alloc((size_t)NN * 8 * 4);
    float*          A1   = (float*)alloc(DIN * 4);
    float*          B1   = (float*)alloc(DIN * 4);
    float*          A2   = (float*)alloc(HID * 4);
    float*          B2   = (float*)alloc(HID * 4);
    int*            offs = (int*)alloc((NN + 1) * 4);
    int*            cur  = (int*)alloc(NN * 4);
    int*            ssrc = (int*)alloc(ET * 4);
    char* zbase = p;
    float* colsum1 = (float*)alloc(DIN * 4);
    float* colsq1  = (float*)alloc(DIN * 4);
    float* colsum2 = (float*)alloc(HID * 4);
    float* colsq2  = (float*)alloc(HID * 4);
    int*   deg     = (int*)alloc(NN * 4);
    size_t zlen = (size_t)(p - zbase);
    hipMemsetAsync(zbase, 0, zlen, stream);

    // BN1 -> hn [NN,KP] bf16
    bn1_stats<<<80, 256, 0, stream>>>(x, colsum1, colsq1);
    bn1_scale<<<1, 256, 0, stream>>>(colsum1, colsq1, gamma1, beta1, A1, B1);
    bn1_apply<<<(NN * KP + 255) / 256, 256, 0, stream>>>(x, A1, B1, hn);
    // W1 transpose+pad+cvt (f32 -> bf16 [HID,KP])
    w1_transpose<<<(HID * KP + 255) / 256, 256, 0, stream>>>(Wl1, Wr1, wlt, wrt);
    // GEMM1 (MFMA, LDS-staged B) -> xl1, xr1
    gemm1_kernel<<<dim3((NN + 127) / 128, HID / 64, 2), 256, 0, stream>>>(hn, wlt, wrt, bl1, br1, xl1, xr1);
    // edge sort by dst
    edge_hist<<<(ET + 255) / 256, 256, 0, stream>>>(ei, deg);
    scan_kernel<<<1, 1024, 0, stream>>>(deg, offs, cur);
    edge_scatter<<<(ET + 255) / 256, 256, 0, stream>>>(ei, cur, ssrc);
    // GAT1 fused single-gather -> agg (bf16, +bias1) ; agg aliases xr1
    gat1_node<<<NN, 256, 0, stream>>>(xl1, xr1, att1, bias1, offs, ssrc, agg);
    // BN2 + leaky(0.01) in-place on agg -> h2
    bn2_stats<<<80, 256, 0, stream>>>(agg, colsum2, colsq2);
    bn2_scale<<<1, 1024, 0, stream>>>(colsum2, colsq2, gamma2, beta2, A2, B2);
    bn2_apply<<<(NN * HID / 4 + 255) / 256, 256, 0, stream>>>(agg, A2, B2);
    // GEMM2 -> xl2, xr2
    gemm2_kernel<<<NN / 4, 256, 0, stream>>>(agg, Wl2, bl2, Wr2, br2, xl2, xr2);
    // GAT2 -> out (f32)
    gat2_node<<<NN / 4, 256, 0, stream>>>(xl2, xr2, att2, bias2, offs, ssrc, out);
}

// Round 10
// 284.395 us; speedup vs baseline: 1.6435x; 1.2224x over previous
//
#include <hip/hip_runtime.h>

// ---------------- problem constants ----------------
#define NN   10000     // nodes
#define E0   160000    // raw edges
#define ET   170000    // edges + self loops
#define DIN  165       // input channels
#define KP   192       // DIN padded to 32x for MFMA K-loop
#define HID  1024      // 8 heads * 128
#define NH   8
#define MAXD 192       // max in-degree cap
#define BP   200       // LDS row pitch for gemm1 B-tile
#define K2P  1032      // LDS row pitch for gemm2 B (1024+8: dword pitch 516 = 4 mod 32 -> 2-way free)

// dtypes (settled r6): ALL float tensors f32, edge_index int32, OUTPUT f32.

typedef __bf16 bf16x8 __attribute__((ext_vector_type(8)));
typedef float  f32x4  __attribute__((ext_vector_type(4)));

__device__ __forceinline__ float bf2f(unsigned short u) {
    unsigned int i = ((unsigned int)u) << 16;
    return __builtin_bit_cast(float, i);
}
__device__ __forceinline__ unsigned short f2bf(float f) {
    unsigned int i = __builtin_bit_cast(unsigned int, f);
    i += 0x7fffu + ((i >> 16) & 1u);   // round-to-nearest-even
    return (unsigned short)(i >> 16);
}
__device__ __forceinline__ float fin(float x) {
    return fminf(fmaxf(x, -1e30f), 1e30f);
}
__device__ __forceinline__ int clampi(int s) {
    return min(max(s, 0), NN - 1);
}
__device__ __forceinline__ void unpack8(uint4 u, float* f) {
    f[0]=bf2f((unsigned short)(u.x)); f[1]=bf2f((unsigned short)(u.x>>16));
    f[2]=bf2f((unsigned short)(u.y)); f[3]=bf2f((unsigned short)(u.y>>16));
    f[4]=bf2f((unsigned short)(u.z)); f[5]=bf2f((unsigned short)(u.z>>16));
    f[6]=bf2f((unsigned short)(u.w)); f[7]=bf2f((unsigned short)(u.w>>16));
}

// ---------------- debug ----------------
__global__ __launch_bounds__(256) void debug_fill(float* __restrict__ out, float val) {
    int i = blockIdx.x * 256 + threadIdx.x;
    if (i < NN) out[i] = val;
}

// ---------------- BN1: column stats over x [NN, DIN] f32 ----------------
__global__ __launch_bounds__(256) void bn1_stats(const float* __restrict__ x,
                                                 float* __restrict__ colsum, float* __restrict__ colsq) {
    int r0 = blockIdx.x * 125;
    int c = threadIdx.x;
    if (c >= DIN) return;
    float acc = 0.f, sq = 0.f;
    for (int r = r0; r < r0 + 125; ++r) {
        float v = x[(size_t)r * DIN + c];
        acc += v; sq += v * v;
    }
    atomicAdd(&colsum[c], acc);
    atomicAdd(&colsq[c], sq);
}

__global__ void bn1_scale(const float* __restrict__ colsum, const float* __restrict__ colsq,
                          const float* __restrict__ gamma, const float* __restrict__ beta,
                          float* __restrict__ A, float* __restrict__ B) {
    int c = threadIdx.x;
    if (c >= DIN) return;
    float mu  = colsum[c] * (1.f / NN);
    float var = fmaxf(colsq[c] * (1.f / NN) - mu * mu, 0.f);
    float a = gamma[c] * rsqrtf(var + 1e-5f);
    A[c] = a; B[c] = beta[c] - mu * a;
}

// write normalized, K-padded input hn [NN, KP] bf16
__global__ __launch_bounds__(256) void bn1_apply(const float* __restrict__ x,
                                                 const float* __restrict__ A, const float* __restrict__ B,
                                                 unsigned short* __restrict__ hn) {
    int idx = blockIdx.x * 256 + threadIdx.x;   // NN*KP threads
    if (idx >= NN * KP) return;
    int r = idx / KP, c = idx - r * KP;
    float v = 0.f;
    if (c < DIN) v = fin(x[(size_t)r * DIN + c] * A[c] + B[c]);
    hn[idx] = f2bf(v);
}

// ---------------- transpose+pad+cvt W1: f32 [DIN,HID] -> bf16 [HID,KP] ----------------
__global__ __launch_bounds__(256) void w1_transpose(const float* __restrict__ wl,
                                                    const float* __restrict__ wr,
                                                    unsigned short* __restrict__ wlt,
                                                    unsigned short* __restrict__ wrt) {
    int idx = blockIdx.x * 256 + threadIdx.x;   // HID*KP
    if (idx >= HID * KP) return;
    int n = idx / KP, k = idx - n * KP;
    wlt[idx] = (k < DIN) ? f2bf(wl[(size_t)k * HID + n]) : (unsigned short)0;
    wrt[idx] = (k < DIN) ? f2bf(wr[(size_t)k * HID + n]) : (unsigned short)0;
}

// ---------------- GEMM1 (MFMA, LDS-staged B): hn [NN,KP] @ W [KP,HID] -> xl,xr bf16 ------
__global__ __launch_bounds__(256) void gemm1_kernel(
    const unsigned short* __restrict__ hn,
    const unsigned short* __restrict__ wlt,  // [HID][KP] bf16
    const unsigned short* __restrict__ wrt,
    const float* __restrict__ bl,
    const float* __restrict__ br,
    unsigned short* __restrict__ xl,
    unsigned short* __restrict__ xr) {
    const unsigned short* wt = blockIdx.z ? wrt : wlt;
    const float* bias        = blockIdx.z ? br  : bl;
    unsigned short* xout     = blockIdx.z ? xr  : xl;

    __shared__ unsigned short bs[64 * BP];   // 25.6 KB
    const int tid  = threadIdx.x;
    const int lane = tid & 63;
    const int wave = tid >> 6;
    const int col  = lane & 15;
    const int q    = lane >> 4;
    const int n0   = blockIdx.y * 64;

    for (int idx = tid; idx < 64 * 48; idx += 256) {
        int r = idx / 48, c = idx - r * 48;
        uint2 v = *(const uint2*)(wt + (size_t)(n0 + r) * KP + c * 4);
        *(uint2*)&bs[r * BP + c * 4] = v;
    }
    __syncthreads();

    const int mbase = blockIdx.x * 128 + wave * 32;
    const int am0 = mbase + col;
    const int am1 = am0 + 16;
    const bool aok0 = (am0 < NN), aok1 = (am1 < NN);

    f32x4 acc[2][4];
    #pragma unroll
    for (int m = 0; m < 2; ++m)
        for (int nt = 0; nt < 4; ++nt)
            for (int r = 0; r < 4; ++r) acc[m][nt][r] = 0.f;

    #pragma unroll
    for (int kt = 0; kt < 6; ++kt) {
        const int kk = kt * 32 + q * 8;
        uint4 a0u = make_uint4(0u,0u,0u,0u), a1u = make_uint4(0u,0u,0u,0u);
        if (aok0) a0u = *(const uint4*)(hn + (size_t)am0 * KP + kk);
        if (aok1) a1u = *(const uint4*)(hn + (size_t)am1 * KP + kk);
        bf16x8 a0 = __builtin_bit_cast(bf16x8, a0u);
        bf16x8 a1 = __builtin_bit_cast(bf16x8, a1u);
        #pragma unroll
        for (int nt = 0; nt < 4; ++nt) {
            bf16x8 bf = __builtin_bit_cast(bf16x8, *(const uint4*)&bs[(nt * 16 + col) * BP + kk]);
            acc[0][nt] = __builtin_amdgcn_mfma_f32_16x16x32_bf16(a0, bf, acc[0][nt], 0, 0, 0);
            acc[1][nt] = __builtin_amdgcn_mfma_f32_16x16x32_bf16(a1, bf, acc[1][nt], 0, 0, 0);
        }
    }

    #pragma unroll
    for (int nt = 0; nt < 4; ++nt) {
        const int nc = n0 + nt * 16 + col;
        const float bv = bias[nc];
        #pragma unroll
        for (int m = 0; m < 2; ++m) {
            #pragma unroll
            for (int r = 0; r < 4; ++r) {
                const int row = mbase + m * 16 + q * 4 + r;
                if (row < NN)
                    xout[(size_t)row * HID + nc] = f2bf(fin(acc[m][nt][r] + bv));
            }
        }
    }
}

// ---------------- edge counting-sort by dst ----------------
__global__ __launch_bounds__(256) void edge_hist(const int* __restrict__ ei, int* __restrict__ deg) {
    int e = blockIdx.x * 256 + threadIdx.x;
    if (e >= ET) return;
    int d = (e < E0) ? ei[E0 + e] : (e - E0);
    atomicAdd(&deg[clampi(d)], 1);
}

// single-block scan, 10 elems/thread, 1 barrier
__global__ __launch_bounds__(1024) void scan_kernel(const int* __restrict__ deg,
                                                    int* __restrict__ offs, int* __restrict__ cur) {
    __shared__ int wsum[16];
    const int tid = threadIdx.x;
    const int base = tid * 10;
    int loc[10];
    int run = 0;
    #pragma unroll
    for (int j = 0; j < 10; ++j) {
        int idx = base + j;
        int v = (idx < NN) ? deg[idx] : 0;
        loc[j] = run;
        run += v;
    }
    const int lane = tid & 63;
    const int w = tid >> 6;
    int inc = run;
    #pragma unroll
    for (int s = 1; s < 64; s <<= 1) {
        int t = __shfl_up(inc, s);
        if (lane >= s) inc += t;
    }
    if (lane == 63) wsum[w] = inc;
    __syncthreads();
    int woff = 0;
    #pragma unroll
    for (int k = 0; k < 16; ++k) woff += (k < w) ? wsum[k] : 0;
    const int toff = woff + inc - run;
    #pragma unroll
    for (int j = 0; j < 10; ++j) {
        int idx = base + j;
        if (idx < NN) { int e = toff + loc[j]; offs[idx] = e; cur[idx] = e; }
    }
    if (tid == 1023) offs[NN] = woff + inc;
}

__global__ __launch_bounds__(256) void edge_scatter(const int* __restrict__ ei,
                                                    int* __restrict__ cur, int* __restrict__ ssrc) {
    int e = blockIdx.x * 256 + threadIdx.x;
    if (e >= ET) return;
    int s, d;
    if (e < E0) { s = ei[e]; d = ei[E0 + e]; }
    else        { s = e - E0; d = e - E0; }
    int pos = atomicAdd(&cur[clampi(d)], 1);
    if (pos >= 0 && pos < ET) ssrc[pos] = clampi(s);
}

// ---------------- GAT1 fused single-gather: logits+softmax+aggregate -> agg bf16 ----
// NOTE: agg aliases xr1 (row i read only by block i before sync#1; written after sync#2).
__global__ __launch_bounds__(256) void gat1_node(
    const unsigned short* __restrict__ xl1, const unsigned short* xr1,
    const float* __restrict__ att1, const float* __restrict__ bias1,
    const int* __restrict__ offs, const int* __restrict__ ssrc,
    unsigned short* agg) {
    const int i    = blockIdx.x;
    const int tid  = threadIdx.x;
    const int lane = tid & 63;
    const int wave = tid >> 6;
    __shared__ float o_lds[4][64][16];   // 16 KB
    __shared__ float s_lds[4][NH];
    __shared__ int   src_lds[MAXD];
    const int e0 = offs[i];
    const int deg = max(min(offs[i + 1] - e0, MAXD), 0);

    float xr_r[16], att_r[16];
    {
        const uint4* xp = (const uint4*)(xr1 + (size_t)i * HID + lane * 16);
        uint4 u0 = xp[0], u1 = xp[1];
        unpack8(u0, xr_r); unpack8(u1, xr_r + 8);
        const float4* ap = (const float4*)(att1 + lane * 16);
        float4 a0 = ap[0], a1 = ap[1], a2 = ap[2], a3 = ap[3];
        att_r[0]=a0.x; att_r[1]=a0.y; att_r[2]=a0.z; att_r[3]=a0.w;
        att_r[4]=a1.x; att_r[5]=a1.y; att_r[6]=a1.z; att_r[7]=a1.w;
        att_r[8]=a2.x; att_r[9]=a2.y; att_r[10]=a2.z; att_r[11]=a2.w;
        att_r[12]=a3.x; att_r[13]=a3.y; att_r[14]=a3.z; att_r[15]=a3.w;
    }
    for (int e = tid; e < deg; e += 256) src_lds[e] = clampi(ssrc[e0 + e]);
    __syncthreads();   // #1 — all xr1 reads complete (alias safety)

    float o[16];
    #pragma unroll
    for (int j = 0; j < 16; ++j) o[j] = 0.f;
    float s = 0.f;

    for (int e = wave; e < deg; e += 4) {
        const int sidx = src_lds[e];
        const uint4* xp = (const uint4*)(xl1 + (size_t)sidx * HID + lane * 16);
        uint4 u0 = xp[0], u1 = xp[1];
        float xv[16];
        unpack8(u0, xv); unpack8(u1, xv + 8);
        float p = 0.f;
        #pragma unroll
        for (int j = 0; j < 16; ++j) {
            float v = xv[j] + xr_r[j];
            v = fmaxf(v, 0.2f * v);            // leaky_relu 0.2
            p = fmaf(att_r[j], v, p);
        }
        p += __shfl_xor(p, 1); p += __shfl_xor(p, 2); p += __shfl_xor(p, 4);
        const float a = __expf(fminf(fin(p), 50.f));
        s += a;
        #pragma unroll
        for (int j = 0; j < 16; ++j) o[j] = fmaf(a, xv[j], o[j]);
    }

    #pragma unroll
    for (int j = 0; j < 4; ++j)
        *(float4*)&o_lds[wave][lane][j * 4] = make_float4(o[j*4], o[j*4+1], o[j*4+2], o[j*4+3]);
    if ((lane & 7) == 0) s_lds[wave][lane >> 3] = s;
    __syncthreads();   // #2 — agg (= xr1) writes only after this

    const int h  = tid >> 5;
    const int lo = tid >> 2;
    const int eo = (tid & 3) * 4;
    const float stot = s_lds[0][h] + s_lds[1][h] + s_lds[2][h] + s_lds[3][h];
    const float inv = 1.f / (stot + 1e-16f);
    float4 r = make_float4(0.f, 0.f, 0.f, 0.f);
    #pragma unroll
    for (int w = 0; w < 4; ++w) {
        float4 t = *(const float4*)&o_lds[w][lo][eo];
        r.x += t.x; r.y += t.y; r.z += t.z; r.w += t.w;
    }
    const float* bp = bias1 + tid * 4;
    ushort4 ov;
    ov.x = f2bf(fin(r.x * inv + bp[0]));
    ov.y = f2bf(fin(r.y * inv + bp[1]));
    ov.z = f2bf(fin(r.z * inv + bp[2]));
    ov.w = f2bf(fin(r.w * inv + bp[3]));
    *(ushort4*)(agg + (size_t)i * HID + tid * 4) = ov;
}

// ---------------- BN2 over agg [NN,HID] bf16 ----------------
__global__ __launch_bounds__(256) void bn2_stats(const unsigned short* __restrict__ agg,
                                                 float* __restrict__ colsum, float* __restrict__ colsq) {
    int r0 = blockIdx.x * 125;
    int t = threadIdx.x;
    float s0=0,s1=0,s2=0,s3=0,q0=0,q1=0,q2=0,q3=0;
    for (int r = r0; r < r0 + 125; ++r) {
        const ushort4 u = *(const ushort4*)(agg + (size_t)r * HID + t * 4);
        float v0=bf2f(u.x), v1=bf2f(u.y), v2=bf2f(u.z), v3=bf2f(u.w);
        s0+=v0; q0+=v0*v0; s1+=v1; q1+=v1*v1;
        s2+=v2; q2+=v2*v2; s3+=v3; q3+=v3*v3;
    }
    atomicAdd(&colsum[t*4+0], s0); atomicAdd(&colsq[t*4+0], q0);
    atomicAdd(&colsum[t*4+1], s1); atomicAdd(&colsq[t*4+1], q1);
    atomicAdd(&colsum[t*4+2], s2); atomicAdd(&colsq[t*4+2], q2);
    atomicAdd(&colsum[t*4+3], s3); atomicAdd(&colsq[t*4+3], q3);
}

__global__ __launch_bounds__(1024) void bn2_scale(const float* __restrict__ colsum, const float* __restrict__ colsq,
                                                  const float* __restrict__ gamma, const float* __restrict__ beta,
                                                  float* __restrict__ A, float* __restrict__ B) {
    int c = threadIdx.x;
    float mu  = colsum[c] * (1.f / NN);
    float var = fmaxf(colsq[c] * (1.f / NN) - mu * mu, 0.f);
    float a = gamma[c] * rsqrtf(var + 1e-5f);
    A[c] = a; B[c] = beta[c] - mu * a;
}

// in-place: agg(bf16) -> h2(bf16), BN affine + leaky_relu(0.01)
__global__ __launch_bounds__(256) void bn2_apply(unsigned short* __restrict__ agg,
                                                 const float* __restrict__ A, const float* __restrict__ B) {
    int idx = blockIdx.x * 256 + threadIdx.x;
    int base = idx * 4;
    int c = base & (HID - 1);
    ushort4 u = *(const ushort4*)(agg + base);
    float4 a = *(const float4*)(A + c);
    float4 b = *(const float4*)(B + c);
    float o0 = bf2f(u.x) * a.x + b.x, o1 = bf2f(u.y) * a.y + b.y;
    float o2 = bf2f(u.z) * a.z + b.z, o3 = bf2f(u.w) * a.w + b.w;
    o0 = fmaxf(o0, 0.01f * o0); o1 = fmaxf(o1, 0.01f * o1);   // leaky 0.01
    o2 = fmaxf(o2, 0.01f * o2); o3 = fmaxf(o3, 0.01f * o3);
    ushort4 o; o.x = f2bf(fin(o0)); o.y = f2bf(fin(o1)); o.z = f2bf(fin(o2)); o.w = f2bf(fin(o3));
    *(ushort4*)(agg + base) = o;
}

// ---------------- W2 prep: stack+transpose+cvt -> w2ct [16][HID] bf16 (cols 0-7=L, 8-15=R) --
__global__ __launch_bounds__(256) void w2_prep(const float* __restrict__ wl2,
                                               const float* __restrict__ wr2,
                                               unsigned short* __restrict__ w2ct) {
    int idx = blockIdx.x * 256 + threadIdx.x;   // 16*HID
    if (idx >= 16 * HID) return;
    int n = idx >> 10, k = idx & (HID - 1);
    float v = (n < 8) ? wl2[k * 8 + n] : wr2[k * 8 + (n - 8)];
    w2ct[idx] = f2bf(v);
}

// ---------------- GEMM2 (MFMA, r10): h2 [NN,HID] @ B[HID,16] -> xl2|xr2 [NN,8] f32 -------
// B = [Wl2 | Wr2] stacked to 16 cols; one wave per 16-row m-tile; 32 MFMAs over K=1024.
// Was: per-lane W2 reads 512B apart -> 64-way uncoalesced, latency-bound 76us @ 8% VALU.
__global__ __launch_bounds__(256) void gemm2_kernel(
    const unsigned short* __restrict__ h2,
    const unsigned short* __restrict__ w2ct,   // [16][HID] bf16
    const float* __restrict__ bl2, const float* __restrict__ br2,
    float* __restrict__ xl2, float* __restrict__ xr2) {
    __shared__ unsigned short bs[16 * K2P];   // 33 KB
    const int tid  = threadIdx.x;
    const int lane = tid & 63;
    const int wave = tid >> 6;
    const int col  = lane & 15;
    const int q    = lane >> 4;

    // stage B: 16 rows x 1024, uint2 granules (4 bf16), coalesced
    for (int idx = tid; idx < 16 * 256; idx += 256) {
        int r = idx >> 8, c = idx & 255;
        uint2 v = *(const uint2*)(w2ct + (size_t)r * HID + c * 4);
        *(uint2*)&bs[r * K2P + c * 4] = v;
    }
    __syncthreads();

    const int mtile = blockIdx.x * 4 + wave;
    if (mtile >= NN / 16) return;        // 625 tiles exactly; tail waves exit after barrier
    const int m0 = mtile * 16;
    const int am = m0 + col;

    f32x4 acc;
    acc[0] = acc[1] = acc[2] = acc[3] = 0.f;
    #pragma unroll
    for (int kt = 0; kt < 32; ++kt) {
        const int kk = kt * 32 + q * 8;
        bf16x8 af = __builtin_bit_cast(bf16x8, *(const uint4*)(h2 + (size_t)am * HID + kk));
        bf16x8 bf = __builtin_bit_cast(bf16x8, *(const uint4*)&bs[col * K2P + kk]);
        acc = __builtin_amdgcn_mfma_f32_16x16x32_bf16(af, bf, acc, 0, 0, 0);
    }

    // D: row = m0 + q*4 + r, col = lane&15 (cols 0-7 -> xl2, 8-15 -> xr2)
    const float bv = (col < 8) ? bl2[col] : br2[col - 8];
    float* outp = (col < 8) ? (xl2 + col) : (xr2 + (col - 8));
    #pragma unroll
    for (int r = 0; r < 4; ++r) {
        const int row = m0 + q * 4 + r;
        outp[row * 8] = fin(acc[r] + bv);
    }
}

// ---------------- GAT2 per-node (wave per node), mean over heads -> f32 out ----------------
__global__ __launch_bounds__(256) void gat2_node(
    const float* __restrict__ xl2, const float* __restrict__ xr2,
    const float* __restrict__ att2, const float* __restrict__ bias2,
    const int* __restrict__ offs, const int* __restrict__ ssrc,
    float* __restrict__ out) {
    const int lane = threadIdx.x & 63;
    const int wave = threadIdx.x >> 6;
    const int i = blockIdx.x * 4 + wave;
    const int h = lane & 7, slot = lane >> 3;
    const int e0 = offs[i];
    const int e1 = max(offs[i + 1], e0);
    const float xr_h = xr2[i * 8 + h];
    const float att_h = att2[h];
    float m = -1e30f;
    for (int eb = e0; eb < e1; eb += 8) {
        int e = eb + slot;
        float lg = -1e30f;
        if (e < e1) {
            float v = xl2[clampi(ssrc[e]) * 8 + h] + xr_h;
            v = fmaxf(v, 0.2f * v);
            lg = fin(att_h * v);
        }
        m = fmaxf(m, lg);
    }
    m = fmaxf(m, __shfl_xor(m, 8)); m = fmaxf(m, __shfl_xor(m, 16)); m = fmaxf(m, __shfl_xor(m, 32));
    float ssum = 0.f, wsum = 0.f;
    for (int eb = e0; eb < e1; eb += 8) {
        int e = eb + slot;
        if (e < e1) {
            float xlv = xl2[clampi(ssrc[e]) * 8 + h];
            float v = xlv + xr_h;
            v = fmaxf(v, 0.2f * v);
            float a = __expf(fminf(fin(att_h * v) - m, 0.f));
            ssum += a; wsum += a * xlv;
        }
    }
    ssum += __shfl_xor(ssum, 8); ssum += __shfl_xor(ssum, 16); ssum += __shfl_xor(ssum, 32);
    wsum += __shfl_xor(wsum, 8); wsum += __shfl_xor(wsum, 16); wsum += __shfl_xor(wsum, 32);
    float v = fin(wsum / (ssum + 1e-16f));
    v += __shfl_xor(v, 1); v += __shfl_xor(v, 2); v += __shfl_xor(v, 4);
    if (lane == 0) out[i] = fin(v * 0.125f + bias2[0]);
}

// ---------------- launch ----------------
extern "C" void kernel_launch(void* const* d_in, const int* in_sizes, int n_in,
                              void* d_out, int out_size, void* d_ws, size_t ws_size,
                              hipStream_t stream) {
    float* out = (float*)d_out;   // reference output dtype is float32

    static const int expected[18] = {
        NN * DIN, DIN, DIN, DIN * HID, HID, DIN * HID, HID, HID, HID,
        HID, HID, HID * NH, NH, HID * NH, NH, NH, 1, 2 * E0
    };
    if (n_in != 18) {
        debug_fill<<<(NN + 255) / 256, 256, 0, stream>>>(out, 8192.f + 64.f * (float)n_in);
        return;
    }
    for (int i = 0; i < 18; ++i) {
        if (in_sizes[i] != expected[i]) {
            debug_fill<<<(NN + 255) / 256, 256, 0, stream>>>(out, 4096.f + 32.f * (float)i);
            return;
        }
    }

    const float* x      = (const float*)d_in[0];
    const float* gamma1 = (const float*)d_in[1];
    const float* beta1  = (const float*)d_in[2];
    const float* Wl1    = (const float*)d_in[3];
    const float* bl1    = (const float*)d_in[4];
    const float* Wr1    = (const float*)d_in[5];
    const float* br1    = (const float*)d_in[6];
    const float* att1   = (const float*)d_in[7];
    const float* bias1  = (const float*)d_in[8];
    const float* gamma2 = (const float*)d_in[9];
    const float* beta2  = (const float*)d_in[10];
    const float* Wl2    = (const float*)d_in[11];
    const float* bl2    = (const float*)d_in[12];
    const float* Wr2    = (const float*)d_in[13];
    const float* br2    = (const float*)d_in[14];
    const float* att2   = (const float*)d_in[15];
    const float* bias2  = (const float*)d_in[16];
    const int*   ei     = (const int*)d_in[17];

    char* p = (char*)d_ws;
    auto alloc = [&](size_t bytes) -> void* {
        void* r = (void*)p;
        p += (bytes + 255) & ~(size_t)255;
        return r;
    };
    unsigned short* xl1  = (unsigned short*)alloc((size_t)NN * HID * 2);  // 20.48 MB
    unsigned short* xr1  = (unsigned short*)alloc((size_t)NN * HID * 2);  // 20.48 MB
    unsigned short* agg  = xr1;                                           // ALIAS (see gat1_node)
    unsigned short* hn   = (unsigned short*)alloc((size_t)NN * KP * 2);   // 3.84 MB
    unsigned short* wlt  = (unsigned short*)alloc((size_t)HID * KP * 2);  // 0.39 MB
    unsigned short* wrt  = (unsigned short*)alloc((size_t)HID * KP * 2);  // 0.39 MB
    unsigned short* w2ct = (unsigned short*)alloc((size_t)16 * HID * 2);  // 32 KB
    float*          xl2  = (float*)alloc((size_t)NN * 8 * 4);
    float*          xr2  = (float*)alloc((size_t)NN * 8 * 4);
    float*          A1   = (float*)alloc(DIN * 4);
    float*          B1   = (float*)alloc(DIN * 4);
    float*          A2   = (float*)alloc(HID * 4);
    float*          B2   = (float*)alloc(HID * 4);
    int*            offs = (int*)alloc((NN + 1) * 4);
    int*            cur  = (int*)alloc(NN * 4);
    int*            ssrc = (int*)alloc(ET * 4);
    char* zbase = p;
    float* colsum1 = (float*)alloc(DIN * 4);
    float* colsq1  = (float*)alloc(DIN * 4);
    float* colsum2 = (float*)alloc(HID * 4);
    float* colsq2  = (float*)alloc(HID * 4);
    int*   deg     = (int*)alloc(NN * 4);
    size_t zlen = (size_t)(p - zbase);
    hipMemsetAsync(zbase, 0, zlen, stream);

    // BN1 -> hn [NN,KP] bf16
    bn1_stats<<<80, 256, 0, stream>>>(x, colsum1, colsq1);
    bn1_scale<<<1, 256, 0, stream>>>(colsum1, colsq1, gamma1, beta1, A1, B1);
    bn1_apply<<<(NN * KP + 255) / 256, 256, 0, stream>>>(x, A1, B1, hn);
    // W1 transpose+pad+cvt (f32 -> bf16 [HID,KP])
    w1_transpose<<<(HID * KP + 255) / 256, 256, 0, stream>>>(Wl1, Wr1, wlt, wrt);
    // GEMM1 (MFMA, LDS-staged B) -> xl1, xr1
    gemm1_kernel<<<dim3((NN + 127) / 128, HID / 64, 2), 256, 0, stream>>>(hn, wlt, wrt, bl1, br1, xl1, xr1);
    // edge sort by dst
    edge_hist<<<(ET + 255) / 256, 256, 0, stream>>>(ei, deg);
    scan_kernel<<<1, 1024, 0, stream>>>(deg, offs, cur);
    edge_scatter<<<(ET + 255) / 256, 256, 0, stream>>>(ei, cur, ssrc);
    // GAT1 fused single-gather -> agg (bf16, +bias1) ; agg aliases xr1
    gat1_node<<<NN, 256, 0, stream>>>(xl1, xr1, att1, bias1, offs, ssrc, agg);
    // BN2 + leaky(0.01) in-place on agg -> h2
    bn2_stats<<<80, 256, 0, stream>>>(agg, colsum2, colsq2);
    bn2_scale<<<1, 1024, 0, stream>>>(colsum2, colsq2, gamma2, beta2, A2, B2);
    bn2_apply<<<(NN * HID / 4 + 255) / 256, 256, 0, stream>>>(agg, A2, B2);
    // W2 prep + GEMM2 (MFMA, stacked B) -> xl2, xr2
    w2_prep<<<(16 * HID + 255) / 256, 256, 0, stream>>>(Wl2, Wr2, w2ct);
    gemm2_kernel<<<(NN / 16 + 3) / 4, 256, 0, stream>>>(agg, w2ct, bl2, br2, xl2, xr2);
    // GAT2 -> out (f32)
    gat2_node<<<NN / 4, 256, 0, stream>>>(xl2, xr2, att2, bias2, offs, ssrc, out);
}